// Round 10
// baseline (867.516 us; speedup 1.0000x reference)
//
#include <hip/hip_runtime.h>
#include <stdint.h>

#define DI __device__ __forceinline__

typedef unsigned short u16;
typedef unsigned int u32;
typedef __attribute__((ext_vector_type(8))) short short8;
typedef __attribute__((ext_vector_type(4))) float floatx4;

// ---------------- geometry ----------------
constexpr int NPIX = 3600;   // 60*60
constexpr int NK   = 3712;   // 3600 padded to multiple of 128 (zero tail)
constexpr int PP   = 4096;   // 64*64 padded pixel grid (image at [2..61]^2)
constexpr int GUARD= 128;    // guard rows on padded-pixel tensors (shifted reads)
constexpr int CIN  = 2048, CI = 512, CQ = 64;

// ---------------- ws layout (bytes) ----------------
// R1 time-shared: XPM (convs) -> SAF/PBUF (attention) -> SACONV/SCCONV (tail)
constexpr size_t OFF_XPM    = 0;                       // 2*4352*2048*2 = 35,651,584
constexpr size_t OFF_SAF    = 0;                       // 3600*512*4 = 7,372,800
constexpr size_t OFF_PBUF   = 14745600;                // 3600*3712*2 = 26,726,400 -> ends 41,472,000
constexpr size_t OFF_SACONV = 0;                       // 2*4096*512*2 = 8,388,608
constexpr size_t OFF_SCCONV = 8388608;
constexpr size_t R1_END     = 42812416;
constexpr size_t OFF_FEAT1  = R1_END;                  // 8,388,608
constexpr size_t OFF_FEAT2  = OFF_FEAT1 + 8388608;
constexpr size_t OFF_SAPM   = OFF_FEAT2 + 8388608;     // 8,912,896  (CACC 16.8MB borrows SAPM+SCPM during s0c0)
constexpr size_t OFF_SCPM   = OFF_SAPM + 8912896;
constexpr size_t OFF_W      = OFF_SCPM + 8912896;      // big region, 37,748,736 (WTT 1024x18432)
// inside W (time-shared with WTT / each other):
constexpr size_t OFF_WQB = OFF_W;                      // 640*512*2 concat
constexpr size_t OFF_QC  = OFF_W + 655360;             // 2*3600*64*2
constexpr size_t OFF_KC  = OFF_W + 1576960;
constexpr size_t OFF_VC  = OFF_W + 2498560;            // 2*3600*512*2 -> ends +9,871,360
constexpr size_t OFF_WT1 = OFF_W;                      // 512*4608*2 (s1) — QC/KC/VC dead by then
constexpr size_t OFF_WT2 = OFF_W + 4718592;            // 512*4608*2 (c1)
constexpr size_t OFF_VCM = OFF_W + 9871360;            // 2*512*3712*2 = 7,602,176 (shared w/ F2CM)
constexpr size_t OFF_CEN = OFF_W + 17473536;           // 2*512*512*4 = 2,097,152
constexpr size_t OFF_CATT= OFF_W + 19570688;           // 2*512*512*2 = 1,048,576 -> ends +20,619,264
constexpr size_t OFF_WH  = OFF_W + 20619264;           // 120*1024*2 = 245,760
constexpr size_t WS_NEED = OFF_W + 37748736;           // 115,164,160 (proven)

// ---------------- helpers ----------------
DI float b2f(u16 s){ u32 u = ((u32)s)<<16; float f; __builtin_memcpy(&f,&u,4); return f; }
DI u16 f2b(float f){ u32 u; __builtin_memcpy(&u,&f,4); u32 r=(u+0x7fffu+((u>>16)&1u))>>16; return (u16)r; }
DI int pad_of(int n){ int y=n/60, x=n-y*60; return ((y+2)<<6)+x+2; }
DI bool interior(int p){ int py=p>>6, px=p&63; return (py>=2)&&(py<62)&&(px>=2)&&(px<62); }
DI int compact_of(int p){ return ((p>>6)-2)*60 + (p&63) - 2; }
DI void gll16(const void* g, void* l){
  __builtin_amdgcn_global_load_lds((const __attribute__((address_space(1))) void*)g,
                                   (__attribute__((address_space(3))) void*)l, 16, 0, 0);
}
DI float wred_min(float v){
#pragma unroll
  for(int m=32;m;m>>=1) v=fminf(v,__shfl_xor(v,m,64));
  return v;
}
DI float wred_sum(float v){
#pragma unroll
  for(int m=32;m;m>>=1) v+=__shfl_xor(v,m,64);
  return v;
}

// ---------------- NT GEMM: C[M,N] = sum_k A[m,k]*B[n,k] (A,B bf16) ----------------
// NOTE: gridDim.x MUST be a multiple of 8 (or share no A-panels across y/z):
// XCD assignment is round-robin on linear block id; same-x blocks land on one
// XCD only when gridDim.x % 8 == 0 (round-8 regression: 30 -> 2.5x A re-fetch).
// MODE 0: conv epilogue relu(bn(acc)) -> bf16, interior rows. NCAT: gc>=nsplit -> {Cb2,bn2}.
//         DUALZ: bz>>1 selects {A2,B2,Cb2,bn2}, bz&1 = batch.
// MODE 3: plain f32 (SPLITK: atomicAdd into zeroed Cf). SHIFT+SPLITK: flat-g conv loop.
// MODE 5: sc: gamma*acc+resid[gr,gc] -> bf16, interior gr
// MODE 6: qkv concat: gc<64 -> QC(+bq), <128 -> KC(+bk), else VC(+bv); compact rows
// MODE 7: head: N=120 -> 3 f32 output planes in d_out (+bias), interior rows; KCAT2 A-concat
struct GArgs {
  const u16 *A, *A2, *B, *B2; u16 *Cb, *Cb2, *Cb3; float* Cf;
  const u16* resid;
  const float *bn, *bn2, *bias, *bias2, *bias3, *gamma, *lambp, *dR, *dC;
  long sA, sB, sC, sres;
  int M, N, KT, ktps, lda, ldb, ldc, Mclamp, Nclamp, nsplit, ksplit, kps, kblog;
};

template<int MODE, bool SHIFT, bool NCAT, bool DUALZ, int U, bool SPLITK, bool KCAT2=false>
__global__ __launch_bounds__(256) void k_gemm(GArgs g){
  __shared__ alignas(16) short As[U*4096];
  __shared__ alignas(16) short Bs[U*4096];
  const int bz = blockIdx.z;
  const int sel = DUALZ ? (bz>>1) : 0;
  int bt  = DUALZ ? (bz&1)  : bz;
  int slice = 0;
  if constexpr(SPLITK){ bt = bz / g.ksplit; slice = bz - bt*g.ksplit; }
  const u16* Ab = ((DUALZ && sel) ? g.A2 : g.A) + (long)bt*g.sA;
  const u16* Ab2 = KCAT2 ? (g.A2 + (long)bt*g.sA) : nullptr;
  const u16* Bb = ((DUALZ && sel) ? g.B2 : g.B) + (long)bt*g.sB;
  const int m0 = blockIdx.x*128, n0 = blockIdx.y*128;
  const int tid = threadIdx.x, wid = tid>>6, lane = tid&63;
  const int wr = wid>>1, wc = wid&1;
  const int fr = lane&15, fq = lane>>4;
  const int srow = lane>>2;
  const int swz = ((lane&3) ^ ((lane>>3)&3)) << 3;   // swizzled 8-short slot within 32-short row

  long raB[2], rbB[2];
#pragma unroll
  for(int h=0;h<2;h++){
    long ra = m0 + wid*32 + h*16 + srow;
    if (!SHIFT) ra = (ra > g.Mclamp) ? (long)g.Mclamp : ra;
    raB[h] = ra*(long)g.lda + swz;
    long rb = n0 + wid*32 + h*16 + srow;
    rb = (rb > g.Nclamp) ? (long)g.Nclamp : rb;
    rbB[h] = rb*(long)g.ldb + swz;
  }
  const int ldsOff[2] = { (wid*32)*64, (wid*32+16)*64 };   // byte offsets within one buffer
  const int rswz = (fq ^ ((fr>>1)&3)) << 3;                // read-side slot (same involution)
  const int aRdO = (wr*64+fr)*32 + rswz;                   // shorts, within one buffer
  const int bRdO = (wc*64+fr)*32 + rswz;

  floatx4 acc[4][4];
#pragma unroll
  for(int i=0;i<4;i++)
#pragma unroll
    for(int j=0;j<4;j++)
#pragma unroll
      for(int e=0;e<4;e++) acc[i][j][e]=0.f;

  if constexpr(SHIFT && SPLITK){
    // flat K-step index g = s*KB + kb over [kt0, ktN); KB = ktps = 1<<kblog
    const int KBm1 = g.ktps - 1;
    const int kt0 = slice*g.kps;
    const int ktN = min(g.KT, kt0 + g.kps);
    for(int kt=kt0; kt<ktN; kt+=U){
      __syncthreads();
#pragma unroll
      for(int u=0;u<U;++u){
        const int gu = kt+u;
        if (gu < ktN){
          const int s_ = gu >> g.kblog;
          const int s3 = s_/3;
          const long aoff = (long)(s3*64 + (s_-s3*3) - 65)*g.lda + ((long)(gu & KBm1)<<5);
          const long boff = (long)gu<<5;
#pragma unroll
          for(int h=0;h<2;h++){
            gll16(Ab + raB[h] + aoff, (char*)As + u*8192 + ldsOff[h]);
            gll16(Bb + rbB[h] + boff, (char*)Bs + u*8192 + ldsOff[h]);
          }
        }
      }
      __syncthreads();
#pragma unroll
      for(int u=0;u<U;++u){
        if (kt+u < ktN){
          short8 af[4], bfv[4];
#pragma unroll
          for(int mi=0;mi<4;mi++) af[mi]  = *(const short8*)(As + u*4096 + aRdO + mi*512);
#pragma unroll
          for(int ni=0;ni<4;ni++) bfv[ni] = *(const short8*)(Bs + u*4096 + bRdO + ni*512);
#pragma unroll
          for(int mi=0;mi<4;mi++)
#pragma unroll
            for(int ni=0;ni<4;ni++)
              acc[mi][ni] = __builtin_amdgcn_mfma_f32_16x16x32_bf16(af[mi], bfv[ni], acc[mi][ni], 0,0,0);
        }
      }
    }
  } else if constexpr(SHIFT){
    const int KB = g.ktps;
    for(int s=0; s<9; ++s){
      const long aoff = (long)((s/3)*64 + (s-(s/3)*3) - 65)*g.lda; // (ky-1)*64+(kx-1)
      const long boff = (long)s*KB*32;
      for(int kb=0; kb<KB; kb+=U){
        __syncthreads();
#pragma unroll
        for(int u=0;u<U;++u){
          const int ko = (kb+u)*32;
#pragma unroll
          for(int h=0;h<2;h++){
            gll16(Ab + raB[h] + aoff + ko, (char*)As + u*8192 + ldsOff[h]);
            gll16(Bb + rbB[h] + boff + ko, (char*)Bs + u*8192 + ldsOff[h]);
          }
        }
        __syncthreads();
#pragma unroll
        for(int u=0;u<U;++u){
          short8 af[4], bfv[4];
#pragma unroll
          for(int mi=0;mi<4;mi++) af[mi]  = *(const short8*)(As + u*4096 + aRdO + mi*512);
#pragma unroll
          for(int ni=0;ni<4;ni++) bfv[ni] = *(const short8*)(Bs + u*4096 + bRdO + ni*512);
#pragma unroll
          for(int mi=0;mi<4;mi++)
#pragma unroll
            for(int ni=0;ni<4;ni++)
              acc[mi][ni] = __builtin_amdgcn_mfma_f32_16x16x32_bf16(af[mi], bfv[ni], acc[mi][ni], 0,0,0);
        }
      }
    }
  } else {
    int kt0 = 0, ktN = g.KT;
    if constexpr(SPLITK){ kt0 = slice*g.kps; ktN = min(g.KT, kt0+g.kps); }
    for(int kt=kt0; kt<ktN; kt+=U){
      __syncthreads();
#pragma unroll
      for(int u=0;u<U;++u){
        if (kt+u < ktN){
          int ko = kt+u;
          const u16* srcA = Ab;
          if constexpr(KCAT2){ if (ko >= (g.KT>>1)){ srcA = Ab2; ko -= (g.KT>>1); } }
          const int koB = (kt+u)*32;
#pragma unroll
          for(int h=0;h<2;h++){
            gll16(srcA + raB[h] + ko*32, (char*)As + u*8192 + ldsOff[h]);
            gll16(Bb + rbB[h] + koB, (char*)Bs + u*8192 + ldsOff[h]);
          }
        }
      }
      __syncthreads();
#pragma unroll
      for(int u=0;u<U;++u){
        if (kt+u < ktN){
          short8 af[4], bfv[4];
#pragma unroll
          for(int mi=0;mi<4;mi++) af[mi]  = *(const short8*)(As + u*4096 + aRdO + mi*512);
#pragma unroll
          for(int ni=0;ni<4;ni++) bfv[ni] = *(const short8*)(Bs + u*4096 + bRdO + ni*512);
#pragma unroll
          for(int mi=0;mi<4;mi++)
#pragma unroll
            for(int ni=0;ni<4;ni++)
              acc[mi][ni] = __builtin_amdgcn_mfma_f32_16x16x32_bf16(af[mi], bfv[ni], acc[mi][ni], 0,0,0);
        }
      }
    }
  }

  float* Cf = (MODE==3) ? g.Cf + (long)bt*g.sC : nullptr;
  const u16* Rb = (MODE==5) ? g.resid + (long)bt*g.sres : nullptr;
  float gamv=0.f;
  if constexpr(MODE==5) gamv = *g.gamma;

#pragma unroll
  for(int ni=0;ni<4;ni++){
    const int gc = n0 + wc*64 + ni*16 + fr;
    if (gc >= g.N) continue;
    if constexpr(MODE==0){
      const float* bnP = g.bn; u16* CbP = g.Cb; int oc = gc;
      if constexpr(DUALZ){ if (sel){ bnP = g.bn2; CbP = g.Cb2; } }
      if constexpr(NCAT){ if (gc >= g.nsplit){ bnP = g.bn2; CbP = g.Cb2; oc = gc - g.nsplit; } }
      CbP += (long)bt*g.sC;
      const float s_=bnP[oc], bb=bnP[CI+oc], mm=bnP[2*CI+oc], vv=bnP[3*CI+oc];
      const float cA = s_*rsqrtf(vv+1e-5f), cB = bb - cA*mm;
#pragma unroll
      for(int mi=0;mi<4;mi++)
#pragma unroll
        for(int j=0;j<4;j++){
          const int gr = m0 + wr*64 + mi*16 + fq*4 + j;
          if (interior(gr)) CbP[(size_t)gr*g.ldc + oc] = f2b(fmaxf(cA*acc[mi][ni][j]+cB, 0.f));
        }
    } else if constexpr(MODE==6){
      u16* dst; int col, ld; float bs;
      if (gc < 64){ dst = g.Cb  + (long)bt*((long)NPIX*CQ); col=gc;     ld=CQ; bs=g.bias[gc]; }
      else if (gc < 128){ dst = g.Cb2 + (long)bt*((long)NPIX*CQ); col=gc-64; ld=CQ; bs=g.bias2[gc-64]; }
      else { dst = g.Cb3 + (long)bt*((long)NPIX*CI); col=gc-128; ld=CI; bs=g.bias3[gc-128]; }
#pragma unroll
      for(int mi=0;mi<4;mi++)
#pragma unroll
        for(int j=0;j<4;j++){
          const int gr = m0 + wr*64 + mi*16 + fq*4 + j;
          if (interior(gr)) dst[(size_t)compact_of(gr)*ld + col] = f2b(acc[mi][ni][j] + bs);
        }
    } else if constexpr(MODE==3){
#pragma unroll
      for(int mi=0;mi<4;mi++)
#pragma unroll
        for(int j=0;j<4;j++){
          const int gr = m0 + wr*64 + mi*16 + fq*4 + j;
          if (gr < g.M){
            if constexpr(SPLITK) atomicAdd(&Cf[(size_t)gr*g.ldc + gc], acc[mi][ni][j]);
            else Cf[(size_t)gr*g.ldc + gc] = acc[mi][ni][j];
          }
        }
    } else if constexpr(MODE==5){
      u16* CbP = g.Cb + (long)bt*g.sC;
#pragma unroll
      for(int mi=0;mi<4;mi++)
#pragma unroll
        for(int j=0;j<4;j++){
          const int gr = m0 + wr*64 + mi*16 + fq*4 + j;
          if (interior(gr)){ const size_t o=(size_t)gr*g.ldc + gc; CbP[o] = f2b(gamv*acc[mi][ni][j] + b2f(Rb[o])); }
        }
    } else if constexpr(MODE==7){
      size_t hb; int oc; const float* bp;
      if (gc < 40){ hb = 0; oc = gc; bp = g.bias; }
      else if (gc < 80){ hb = 288000; oc = gc-40; bp = g.bias2; }
      else { hb = 576000; oc = gc-80; bp = g.bias3; }
      float* dst = g.Cf + hb + (size_t)bt*144000 + (size_t)oc*3600;
      const float bsv = bp[oc];
#pragma unroll
      for(int mi=0;mi<4;mi++)
#pragma unroll
        for(int j=0;j<4;j++){
          const int gr = m0 + wr*64 + mi*16 + fq*4 + j;
          if (interior(gr)) dst[compact_of(gr)] = acc[mi][ni][j] + bsv;
        }
    }
  }
}

// ---------------- split-K conv epilogue: F1/F2 = relu(bn(CACC)) on interior rows ----------------
__global__ __launch_bounds__(256) void k_bnrelu(const float* __restrict__ cacc,
    const float* __restrict__ bn1, const float* __restrict__ bn2,
    u16* __restrict__ f1, u16* __restrict__ f2){
  const int idx = blockIdx.x*256 + threadIdx.x;   // 460800 = 3600*1024/8
  const int n = idx >> 7, c = (idx & 127) * 8;
  const int p = pad_of(n);
  const float4 v0 = *(const float4*)(cacc + (size_t)p*1024 + c);
  const float4 v1 = *(const float4*)(cacc + (size_t)p*1024 + c + 4);
  const bool second = c >= 512;
  const float* bn = second ? bn2 : bn1;
  u16* f = second ? f2 : f1;
  const int oc = c & 511;
  const float vv[8] = {v0.x,v0.y,v0.z,v0.w,v1.x,v1.y,v1.z,v1.w};
  u16 o[8];
#pragma unroll
  for(int j=0;j<8;j++){
    const int ocj = oc + j;
    const float s = bn[ocj], b = bn[CI+ocj], m = bn[2*CI+ocj], var = bn[3*CI+ocj];
    const float cA = s*rsqrtf(var+1e-5f);
    o[j] = f2b(fmaxf(cA*(vv[j]-m)+b, 0.f));
  }
  uint4 ov; __builtin_memcpy(&ov, o, 16);
  *(uint4*)(f + (size_t)p*CI + oc) = ov;
}

// ---------------- fused energy + softmax -> P bf16 (one batch per launch) ----------------
// 225 blocks x 512 threads: block owns 16 q-rows; 8 waves split the 29 col-tiles.
// Pass-1 scores cached in registers (no recompute); emit via per-wave LDS bounce (coalesced).
__global__ __launch_bounds__(512) void k_esm(const u16* __restrict__ qc, const u16* __restrict__ kc,
    const float* __restrict__ dd, const float* __restrict__ lamp, u16* __restrict__ pb){
  __shared__ float lm[8][16], ll[8][16];
  __shared__ alignas(16) u16 pemit[8][16][128];
  const int tid = threadIdx.x, wave = tid>>6, lane = tid&63;
  const int fr = lane&15, fq = lane>>4;
  const int q0 = blockIdx.x*16;
  const float lam = *lamp;
  const u16* qp = qc + (size_t)(q0+fr)*CQ + fq*8;
  const short8 qa0 = *(const short8*)(qp);
  const short8 qa1 = *(const short8*)(qp + 32);
  float dr[4];
#pragma unroll
  for(int j=0;j<4;j++) dr[j] = dd[q0 + fq*4 + j];
  float m[4], l[4];
#pragma unroll
  for(int j=0;j<4;j++){ m[j] = -3e38f; l[j] = 0.f; }
  float vals[4][8][4];   // cached masked scores, statically indexed (rule #20)

  // pass 1: per-wave online row max + sum, scores cached
#pragma unroll
  for(int tt=0; tt<4; ++tt){
    const int t = wave + tt*8;
    if (t < 29){
      const int n0 = t*128;
      floatx4 s[8]; float dc[8];
#pragma unroll
      for(int ni=0; ni<8; ++ni){
        const int ccol = min(n0 + ni*16 + fr, NPIX-1);
        const u16* kp = kc + (size_t)ccol*CQ + fq*8;
        const short8 b0 = *(const short8*)(kp);
        const short8 b1 = *(const short8*)(kp + 32);
        floatx4 z = {0.f,0.f,0.f,0.f};
        z = __builtin_amdgcn_mfma_f32_16x16x32_bf16(qa0, b0, z, 0,0,0);
        s[ni] = __builtin_amdgcn_mfma_f32_16x16x32_bf16(qa1, b1, z, 0,0,0);
        dc[ni] = dd[ccol];
      }
#pragma unroll
      for(int j=0;j<4;j++){
        float tmax = -3e38f;
#pragma unroll
        for(int ni=0;ni<8;ni++){
          const float td = dr[j] - dc[ni];
          float v = s[ni][j] + lam*td*td;
          if (n0 + ni*16 + fr >= NPIX) v = -3e38f;
          vals[tt][ni][j] = v; tmax = fmaxf(tmax, v);
        }
        tmax = fmaxf(tmax, __shfl_xor(tmax,1,64));
        tmax = fmaxf(tmax, __shfl_xor(tmax,2,64));
        tmax = fmaxf(tmax, __shfl_xor(tmax,4,64));
        tmax = fmaxf(tmax, __shfl_xor(tmax,8,64));
        const float mn = fmaxf(m[j], tmax);
        float ts = 0.f;
#pragma unroll
        for(int ni=0;ni<8;ni++) ts += __expf(vals[tt][ni][j]-mn);
        ts += __shfl_xor(ts,1,64);
        ts += __shfl_xor(ts,2,64);
        ts += __shfl_xor(ts,4,64);
        ts += __shfl_xor(ts,8,64);
        l[j] = l[j]*__expf(m[j]-mn) + ts;
        m[j] = mn;
      }
    }
  }
  if (fr == 0){
#pragma unroll
    for(int j=0;j<4;j++){ lm[wave][fq*4+j] = m[j]; ll[wave][fq*4+j] = l[j]; }
  }
  __syncthreads();
  float M[4], L[4];
#pragma unroll
  for(int j=0;j<4;j++){
    const int row = fq*4 + j;
    float mm = lm[0][row];
#pragma unroll
    for(int w=1;w<8;w++) mm = fmaxf(mm, lm[w][row]);
    float ss = 0.f;
#pragma unroll
    for(int w=0;w<8;w++) ss += ll[w][row]*__expf(lm[w][row]-mm);
    M[j] = mm; L[j] = 1.f/ss;
  }

  // pass 2: normalize cached scores, bounce through per-wave LDS tile, coalesced emit
#pragma unroll
  for(int tt=0; tt<4; ++tt){
    const int t = wave + tt*8;
    if (t < 29){
      const int n0 = t*128;
#pragma unroll
      for(int ni=0;ni<8;ni++)
#pragma unroll
        for(int j=0;j<4;j++)
          pemit[wave][fq*4+j][ni*16+fr] = f2b(__expf(vals[tt][ni][j] - M[j])*L[j]);
      asm volatile("s_waitcnt lgkmcnt(0)" ::: "memory");
#pragma unroll
      for(int it=0; it<4; ++it){
        const int row = it*4 + fq;
        const int c8 = fr*8;
        uint4 v; __builtin_memcpy(&v, &pemit[wave][row][c8], 16);
        *(uint4*)(pb + (size_t)(q0+row)*NK + n0 + c8) = v;
      }
    }
  }
}

// ---------------- zero only guard + ring rows of padded pixel-major tensors ----------------
__global__ __launch_bounds__(256) void k_zring(u16* __restrict__ base, int C, long slabStride){
  const int row = blockIdx.x, slab = blockIdx.y;
  bool z;
  if (row < GUARD || row >= GUARD+PP) z = true;
  else z = !interior(row - GUARD);
  if (!z) return;
  u16* p = base + (size_t)slab*slabStride + (size_t)row*C;
  for (int i = threadIdx.x*8; i < C; i += 256*8){
    uint4 zz = {0,0,0,0};
    *(uint4*)(p + i) = zz;
  }
}

// ---------------- x f32 [B,2048,3600] -> padded pixel-major bf16 [B][4352][2048] ----------------
__global__ __launch_bounds__(256) void k_padx(const float* __restrict__ x, u16* __restrict__ xpm){
  __shared__ alignas(16) u16 t[64][72];
  const int n0 = blockIdx.x*64, c0 = blockIdx.y*64, b = blockIdx.z;
  const float* xb = x + (size_t)b*CIN*NPIX;
  u16* ob = xpm + (size_t)b*(PP+2*GUARD)*CIN + (size_t)GUARD*CIN;
  const int tid = threadIdx.x;
#pragma unroll
  for(int pass=0; pass<2; ++pass){
    const int cl = pass*32 + (tid>>3);
    const int nn = (tid&7)*8;
    const int n = n0 + nn;
    const float* src = xb + (size_t)(c0+cl)*NPIX + n;
    u16 r[8];
    if (n + 7 < NPIX){
      const float4 v0 = *(const float4*)src;
      const float4 v1 = *(const float4*)(src+4);
      r[0]=f2b(v0.x); r[1]=f2b(v0.y); r[2]=f2b(v0.z); r[3]=f2b(v0.w);
      r[4]=f2b(v1.x); r[5]=f2b(v1.y); r[6]=f2b(v1.z); r[7]=f2b(v1.w);
    } else {
#pragma unroll
      for(int j=0;j<8;j++){ const int nj=n+j; r[j] = (nj<NPIX)? f2b(src[j]) : (u16)0; }
    }
    __builtin_memcpy(&t[cl][nn], r, 16);
  }
  __syncthreads();
#pragma unroll
  for(int pass=0; pass<2; ++pass){
    const int nl = pass*32 + (tid>>3);
    const int cc = (tid&7)*8;
    const int n = n0 + nl;
    if (n < NPIX){
      u16 v[8];
#pragma unroll
      for(int j=0;j<8;j++) v[j] = t[cc+j][nl];
      uint4 vv; __builtin_memcpy(&vv, v, 16);
      *(uint4*)(ob + (size_t)pad_of(n)*CIN + c0 + cc) = vv;
    }
  }
}

// ---------------- bf16 [rows, 512] pixel-major -> [512, NK] channel-major (zero tail) ----------------
template<bool PADIN>
__global__ __launch_bounds__(256) void k_to_cm(const u16* __restrict__ in, u16* __restrict__ out,
                                               long sIn, long sOut){
  __shared__ alignas(16) u16 t[64][72];
  const int n0 = blockIdx.x*64, c0 = blockIdx.y*64, b = blockIdx.z;
  const u16* ib = in + (size_t)b*sIn;
  u16* ob = out + (size_t)b*sOut;
  const int tid = threadIdx.x;
#pragma unroll
  for(int pass=0; pass<2; ++pass){
    const int nl = pass*32 + (tid>>3);
    const int cc = (tid&7)*8;
    const int n = n0 + nl;
    uint4 v = {0,0,0,0};
    if (n < NPIX){
      const int r = PADIN ? pad_of(n) : n;
      v = *(const uint4*)(ib + (size_t)r*CI + c0 + cc);
    }
    *(uint4*)&t[nl][cc] = v;
  }
  __syncthreads();
#pragma unroll
  for(int pass=0; pass<2; ++pass){
    const int cl = pass*32 + (tid>>3);
    const int nn = (tid&7)*8;
    const int n = n0 + nn;
    if (n < NK){
      u16 v[8];
#pragma unroll
      for(int j=0;j<8;j++) v[j] = t[nn+j][cl];
      uint4 vv; __builtin_memcpy(&vv, v, 16);
      *(uint4*)(ob + (size_t)(c0+cl)*NK + n) = vv;
    }
  }
}

// ---------------- dual weight transform: w f32 [O,Kc,3,3] -> Wt bf16 [O, 9*Kc] ----------------
__global__ __launch_bounds__(256) void k_wt2(const float* __restrict__ wA, const float* __restrict__ wB,
                                             u16* __restrict__ wtA, u16* __restrict__ wtB, int Kc){
  const float* w = blockIdx.y ? wB : wA;
  u16* wt = blockIdx.y ? wtB : wtA;
  const int idx = blockIdx.x*256 + threadIdx.x;
  const int o = idx / Kc, i = idx - o*Kc;
  u16 v[9];
#pragma unroll
  for(int s=0;s<9;s++) v[s] = f2b(w[(size_t)idx*9 + s]);
#pragma unroll
  for(int s=0;s<9;s++) wt[(size_t)o*9*Kc + (size_t)s*Kc + i] = v[s];
}

// ---------------- f32 -> bf16, three concatenated sources ----------------
__global__ __launch_bounds__(256) void k_cvt3(const float* __restrict__ a, int na,
                                              const float* __restrict__ b, int nb,
                                              const float* __restrict__ c, int nc,
                                              u16* __restrict__ dst){
  const int i = blockIdx.x*256 + threadIdx.x;
  float v;
  if (i < na) v = a[i];
  else if (i < na+nb) v = b[i-na];
  else if (i < na+nb+nc) v = c[i-na-nb];
  else return;
  dst[i] = f2b(v);
}

// ---------------- head weight concat: WH[120][1024] bf16 ----------------
__global__ __launch_bounds__(256) void k_whead(const float* __restrict__ w6, const float* __restrict__ w7,
                                               const float* __restrict__ w8, u16* __restrict__ wh){
  const int idx = blockIdx.x*256 + threadIdx.x;   // 120*1024
  const int r = idx >> 10, k = idx & 1023;
  float v = 0.f;
  if (r < 40) v = w8[r*512 + (k & 511)];
  else if (r < 80){ if (k < 512) v = w6[(r-40)*512 + k]; }
  else { if (k >= 512) v = w7[(r-80)*512 + (k-512)]; }
  wh[idx] = f2b(v);
}

// ---------------- channel softmax ----------------
__global__ __launch_bounds__(256) void k_csoftmax(const float* __restrict__ cen, u16* __restrict__ catt){
  const int c = blockIdx.x, b = blockIdx.y, tid = threadIdx.x;
  const float* e = cen + ((size_t)b*CI + c)*CI;
  u16* o = catt + ((size_t)b*CI + c)*CI;
  __shared__ float red[8];
  const float a0 = e[tid], a1 = e[tid+256];
  float lmin = fminf(a0,a1);
  lmin = wred_min(lmin);
  if((tid&63)==0) red[tid>>6]=lmin;
  __syncthreads();
  const float m0 = fminf(fminf(red[0],red[1]),fminf(red[2],red[3]));
  const float x0 = __expf(m0-a0), x1 = __expf(m0-a1);
  float ls = x0+x1;
  ls = wred_sum(ls);
  if((tid&63)==0) red[4+(tid>>6)]=ls;
  __syncthreads();
  const float inv = 1.f/(red[4]+red[5]+red[6]+red[7]);
  o[tid] = f2b(x0*inv); o[tid+256] = f2b(x1*inv);
}

// ---------------- PV epilogue: SAPM[pad(n),c] = gamma*SAF[n,c] + F1[pad(n),c] ----------------
__global__ __launch_bounds__(256) void k_pv_ep(const float* __restrict__ saf, const u16* __restrict__ f1,
                                               u16* __restrict__ sapm, const float* __restrict__ gamma){
  const int idx = blockIdx.x*256 + threadIdx.x;   // 230400 threads, 8 elems each
  const int n = idx >> 6, c = (idx & 63) * 8;
  const float gam = *gamma;
  const int p = pad_of(n);
  const float4 v0 = *(const float4*)(saf + (size_t)n*CI + c);
  const float4 v1 = *(const float4*)(saf + (size_t)n*CI + c + 4);
  const uint4 rv = *(const uint4*)(f1 + (size_t)p*CI + c);
  const u16* rp = (const u16*)&rv;
  u16 o[8];
  o[0]=f2b(gam*v0.x + b2f(rp[0])); o[1]=f2b(gam*v0.y + b2f(rp[1]));
  o[2]=f2b(gam*v0.z + b2f(rp[2])); o[3]=f2b(gam*v0.w + b2f(rp[3]));
  o[4]=f2b(gam*v1.x + b2f(rp[4])); o[5]=f2b(gam*v1.y + b2f(rp[5]));
  o[6]=f2b(gam*v1.z + b2f(rp[6])); o[7]=f2b(gam*v1.w + b2f(rp[7]));
  uint4 ov; __builtin_memcpy(&ov, o, 16);
  *(uint4*)(sapm + (size_t)p*CI + c) = ov;
}

// ---------------- launch ----------------
extern "C" void kernel_launch(void* const* d_in, const int* in_sizes, int n_in,
                              void* d_out, int out_size, void* d_ws, size_t ws_size,
                              hipStream_t stream){
  (void)in_sizes; (void)n_in; (void)out_size;
  if (ws_size < WS_NEED) return;

  const float* x    = (const float*)d_in[0];
  const float* dd   = (const float*)d_in[1];
  const float* w_s0 = (const float*)d_in[2];
  const float* bn_s0= (const float*)d_in[3];
  const float* wq   = (const float*)d_in[4];
  const float* bq   = (const float*)d_in[5];
  const float* wk   = (const float*)d_in[6];
  const float* bk   = (const float*)d_in[7];
  const float* wv   = (const float*)d_in[8];
  const float* bv   = (const float*)d_in[9];
  const float* gsa  = (const float*)d_in[10];
  const float* lam  = (const float*)d_in[11];
  const float* w_s1 = (const float*)d_in[12];
  const float* bn_s1= (const float*)d_in[13];
  const float* w6   = (const float*)d_in[14];
  const float* b6   = (const float*)d_in[15];
  const float* w_c0 = (const float*)d_in[16];
  const float* bn_c0= (const float*)d_in[17];
  const float* gsc  = (const float*)d_in[18];
  const float* w_c1 = (const float*)d_in[19];
  const float* bn_c1= (const float*)d_in[20];
  const float* w7   = (const float*)d_in[21];
  const float* b7   = (const float*)d_in[22];
  const float* w8   = (const float*)d_in[23];
  const float* b8   = (const float*)d_in[24];

  char* W = (char*)d_ws;
  u16*   XPM   = (u16*)(W + OFF_XPM);
  float* SAF   = (float*)(W + OFF_SAF);
  u16*   PB    = (u16*)(W + OFF_PBUF);
  u16*   SACONV= (u16*)(W + OFF_SACONV);
  u16*   SCCONV= (u16*)(W + OFF_SCCONV);
  u16*   F1    = (u16*)(W + OFF_FEAT1);
  u16*   F2    = (u16*)(W + OFF_FEAT2);
  u16*   SAPM  = (u16*)(W + OFF_SAPM);
  u16*   SCPM  = (u16*)(W + OFF_SCPM);
  float* CACC  = (float*)(W + OFF_SAPM);  // 16.8MB, borrows SAPM+SCPM during s0c0
  u16*   WTT   = (u16*)(W + OFF_W);
  u16*   WQB   = (u16*)(W + OFF_WQB);
  u16*   QC    = (u16*)(W + OFF_QC);
  u16*   KC    = (u16*)(W + OFF_KC);
  u16*   VC    = (u16*)(W + OFF_VC);
  u16*   WT1   = (u16*)(W + OFF_WT1);
  u16*   WT2   = (u16*)(W + OFF_WT2);
  u16*   WH    = (u16*)(W + OFF_WH);
  u16*   VCM   = (u16*)(W + OFF_VCM);
  u16*   F2CM  = VCM;                     // time-shared
  float* CEN   = (float*)(W + OFF_CEN);
  u16*   CATT  = (u16*)(W + OFF_CATT);
  float* OUT   = (float*)d_out;

  // zero guard+ring rows of XPM (interiors fully overwritten by padx)
  k_zring<<<dim3(PP+2*GUARD, 2),256,0,stream>>>(XPM,  CIN, (long)(PP+2*GUARD)*CIN);

  k_padx<<<dim3(57,32,2),256,0,stream>>>(x, XPM);

  // conv s0 + c0 fused (N-concat), per-batch split-K=4, U=2 (32KB LDS -> 4 blocks/CU)
  k_wt2<<<dim3((512*2048)/256, 2),256,0,stream>>>(w_s0, w_c0, WTT, WTT + (size_t)512*9*2048, 2048);
  for(int bb=0; bb<2; ++bb){
    hipMemsetAsync(CACC, 0, (size_t)PP*1024*4, stream);
    GArgs a{};
    a.A = XPM + (size_t)bb*(PP+2*GUARD)*CIN + (size_t)GUARD*CIN;
    a.B = WTT; a.Cf = CACC;
    a.sA = 0; a.sB = 0; a.sC = 0;
    a.M = PP; a.N = 1024; a.KT = 576; a.ktps = 64; a.kblog = 6;
    a.lda = CIN; a.ldb = 9*2048; a.ldc = 1024; a.Mclamp = PP-1; a.Nclamp = 1023;
    a.ksplit = 4; a.kps = 144;
    k_gemm<3,true,false,false,2,true><<<dim3(32,8,4),256,0,stream>>>(a);
    k_bnrelu<<<dim3(460800/256),256,0,stream>>>(CACC, bn_s0, bn_c0,
        F1 + (size_t)bb*PP*CI, F2 + (size_t)bb*PP*CI);
  }
  // ring-zero SAPM+SCPM now that CACC (which borrowed their space) is dead
  k_zring<<<dim3(PP+2*GUARD, 4),256,0,stream>>>(SAPM, CI, (long)(PP+2*GUARD)*CI);

  // bf16 copies of 1x1 weights (concat [wq;wk;wv] = 640x512), one launch
  k_cvt3<<<dim3((64*512+64*512+512*512)/256),256,0,stream>>>(wq, 64*512, wk, 64*512, wv, 512*512, WQB);

  // q,k,v in one GEMM (N=640), U=4
  GArgs q{};
  q.A = F1; q.sA = (long)PP*CI; q.lda = CI;
  q.M = PP; q.Mclamp = PP-1; q.KT = 16; q.ktps = 16;
  q.B = WQB; q.sB = 0; q.ldb = CI; q.N = 640; q.Nclamp = 639;
  q.Cb = QC; q.Cb2 = KC; q.Cb3 = VC; q.bias = bq; q.bias2 = bk; q.bias3 = bv;
  k_gemm<6,false,false,false,4,false><<<dim3(32,5,2),256,0,stream>>>(q);

  k_to_cm<false><<<dim3(NK/64, CI/64, 2),256,0,stream>>>(VC, VCM, (long)NPIX*CI, (long)CI*NK);

  // position attention, per batch: fused energy+softmax -> PV(split-K 4) -> epilogue
  for(int bb=0; bb<2; ++bb){
    k_esm<<<dim3(225),512,0,stream>>>(QC + (size_t)bb*NPIX*CQ, KC + (size_t)bb*NPIX*CQ,
                                      dd + (size_t)bb*NPIX, lam, PB);
    hipMemsetAsync(SAF, 0, (size_t)NPIX*CI*4, stream);
    GArgs p{};
    p.A = PB; p.B = VCM + (size_t)bb*CI*NK;
    p.Cf = SAF;
    p.M = NPIX; p.N = CI; p.KT = NK/32; p.ktps = NK/32;
    p.lda = NK; p.ldb = NK; p.ldc = CI; p.sC = 0;
    p.Mclamp = NPIX-1; p.Nclamp = CI-1;
    p.ksplit = 4; p.kps = NK/128;
    k_gemm<3,false,false,false,4,true><<<dim3(29, 4, 4),256,0,stream>>>(p);
    k_pv_ep<<<dim3(NPIX*CI/8/256),256,0,stream>>>(SAF, F1 + (size_t)bb*PP*CI,
                                                  SAPM + (size_t)bb*(PP+2*GUARD)*CI + (size_t)GUARD*CI, gsa);
  }

  // channel attention: Gram with split-K atomics (U=4)
  k_to_cm<true><<<dim3(NK/64, CI/64, 2),256,0,stream>>>(F2, F2CM, (long)PP*CI, (long)CI*NK);
  hipMemsetAsync(CEN, 0, (size_t)2*CI*CI*4, stream);
  GArgs c{};
  c.A = F2CM; c.B = F2CM; c.Cf = CEN;
  c.sA = (long)CI*NK; c.sB = (long)CI*NK; c.sC = (long)CI*CI;
  c.M = CI; c.N = CI; c.KT = NK/32; c.ktps = NK/32;
  c.lda = NK; c.ldb = NK; c.ldc = CI; c.Mclamp = CI-1; c.Nclamp = CI-1;
  c.ksplit = 8; c.kps = (NK/32 + 7)/8;
  k_gemm<3,false,false,false,4,true><<<dim3(4, 4, 16),256,0,stream>>>(c);
  k_csoftmax<<<dim3(CI,2),256,0,stream>>>(CEN, CATT);
  GArgs s{};
  s.A = F2; s.B = CATT;
  s.Cb = SCPM + (size_t)GUARD*CI;
  s.resid = F2; s.gamma = gsc;
  s.sA = (long)PP*CI; s.sB = (long)CI*CI; s.sC = (long)(PP+2*GUARD)*CI; s.sres = (long)PP*CI;
  s.M = PP; s.N = CI; s.KT = 16; s.ktps = 16;
  s.lda = CI; s.ldb = CI; s.ldc = CI; s.Mclamp = PP-1; s.Nclamp = CI-1;
  k_gemm<5,false,false,false,4,false><<<dim3(32, 4, 2),256,0,stream>>>(s);

  // post convs s1 + c1 fused (DUALZ), U=4
  k_wt2<<<dim3((512*512)/256, 2),256,0,stream>>>(w_s1, w_c1, WT1, WT2, 512);
  k_whead<<<dim3(120*1024/256),256,0,stream>>>(w6, w7, w8, WH);
  GArgs t{};
  t.A = SAPM + (size_t)GUARD*CI; t.A2 = SCPM + (size_t)GUARD*CI;
  t.B = WT1; t.B2 = WT2;
  t.Cb = SACONV; t.Cb2 = SCCONV; t.bn = bn_s1; t.bn2 = bn_c1;
  t.sA = (long)(PP+2*GUARD)*CI; t.sB = 0; t.sC = (long)PP*CI;
  t.M = PP; t.N = CI; t.KT = 144; t.ktps = 16;
  t.lda = CI; t.ldb = 9*512; t.ldc = CI; t.Mclamp = PP-1; t.Nclamp = CI-1;
  k_gemm<0,true,false,true,4,false><<<dim3(32,4,4),256,0,stream>>>(t);

  // fused head GEMM: A=[SACONV|SCCONV] (K=1024), B=WH (N=120), f32 out + bias
  GArgs h{};
  h.A = SACONV; h.A2 = SCCONV; h.B = WH; h.Cf = OUT;
  h.bias = b8; h.bias2 = b6; h.bias3 = b7;
  h.sA = (long)PP*CI; h.sB = 0; h.sC = 0;
  h.M = PP; h.N = 120; h.KT = 32; h.ktps = 32;
  h.lda = CI; h.ldb = 1024; h.ldc = 0; h.Mclamp = PP-1; h.Nclamp = 119;
  k_gemm<7,false,false,false,4,false,true><<<dim3(32,1,2),256,0,stream>>>(h);
}

// Round 11
// 727.327 us; speedup vs baseline: 1.1927x; 1.1927x over previous
//
#include <hip/hip_runtime.h>
#include <stdint.h>

#define DI __device__ __forceinline__

typedef unsigned short u16;
typedef unsigned int u32;
typedef __attribute__((ext_vector_type(8))) short short8;
typedef __attribute__((ext_vector_type(4))) float floatx4;

// ---------------- geometry ----------------
constexpr int NPIX = 3600;   // 60*60
constexpr int NK   = 3712;   // 3600 padded to multiple of 128 (zero tail)
constexpr int PP   = 4096;   // 64*64 padded pixel grid (image at [2..61]^2)
constexpr int GUARD= 128;    // guard rows on padded-pixel tensors (shifted reads)
constexpr int CIN  = 2048, CI = 512, CQ = 64;

// ---------------- ws layout (bytes) ----------------
// R1 time-shared: XPM (convs) -> SAF/PBUF (attention) -> SACONV/SCCONV (tail)
constexpr size_t OFF_XPM    = 0;                       // 2*4352*2048*2 = 35,651,584
constexpr size_t OFF_SAF    = 0;                       // 3600*512*4 = 7,372,800
constexpr size_t OFF_PBUF   = 14745600;                // 3600*3712*2 = 26,726,400 -> ends 41,472,000
constexpr size_t OFF_SACONV = 0;                       // 2*4096*512*2 = 8,388,608
constexpr size_t OFF_SCCONV = 8388608;
constexpr size_t R1_END     = 42812416;
constexpr size_t OFF_FEAT1  = R1_END;                  // 8,388,608
constexpr size_t OFF_FEAT2  = OFF_FEAT1 + 8388608;
constexpr size_t OFF_SAPM   = OFF_FEAT2 + 8388608;     // 8,912,896
constexpr size_t OFF_SCPM   = OFF_SAPM + 8912896;
constexpr size_t OFF_W      = OFF_SCPM + 8912896;      // big region, 37,748,736 (WTT 1024x18432)
// inside W (time-shared with WTT / each other):
constexpr size_t OFF_WQB = OFF_W;                      // 640*512*2 concat
constexpr size_t OFF_QC  = OFF_W + 655360;             // 2*3600*64*2
constexpr size_t OFF_KC  = OFF_W + 1576960;
constexpr size_t OFF_VC  = OFF_W + 2498560;            // 2*3600*512*2 -> ends +9,871,360
constexpr size_t OFF_WT1 = OFF_W;                      // 512*4608*2 (s1) — QC/KC/VC dead by then
constexpr size_t OFF_WT2 = OFF_W + 4718592;            // 512*4608*2 (c1)
constexpr size_t OFF_VCM = OFF_W + 9871360;            // 2*512*3712*2 = 7,602,176 (shared w/ F2CM)
constexpr size_t OFF_CEN = OFF_W + 17473536;           // 2*512*512*4 = 2,097,152
constexpr size_t OFF_CATT= OFF_W + 19570688;           // 2*512*512*2 = 1,048,576 -> ends +20,619,264
constexpr size_t OFF_WH  = OFF_W + 20619264;           // 120*1024*2 = 245,760
constexpr size_t WS_NEED = OFF_W + 37748736;           // 115,164,160 (proven)

// ---------------- helpers ----------------
DI float b2f(u16 s){ u32 u = ((u32)s)<<16; float f; __builtin_memcpy(&f,&u,4); return f; }
DI u16 f2b(float f){ u32 u; __builtin_memcpy(&u,&f,4); u32 r=(u+0x7fffu+((u>>16)&1u))>>16; return (u16)r; }
DI int pad_of(int n){ int y=n/60, x=n-y*60; return ((y+2)<<6)+x+2; }
DI bool interior(int p){ int py=p>>6, px=p&63; return (py>=2)&&(py<62)&&(px>=2)&&(px<62); }
DI int compact_of(int p){ return ((p>>6)-2)*60 + (p&63) - 2; }
DI void gll16(const void* g, void* l){
  __builtin_amdgcn_global_load_lds((const __attribute__((address_space(1))) void*)g,
                                   (__attribute__((address_space(3))) void*)l, 16, 0, 0);
}
DI float wred_min(float v){
#pragma unroll
  for(int m=32;m;m>>=1) v=fminf(v,__shfl_xor(v,m,64));
  return v;
}
DI float wred_sum(float v){
#pragma unroll
  for(int m=32;m;m>>=1) v+=__shfl_xor(v,m,64);
  return v;
}

// ---------------- NT GEMM: C[M,N] = sum_k A[m,k]*B[n,k] (A,B bf16) ----------------
// NOTE: gridDim.x MUST be a multiple of 8 (or share no A-panels across y/z):
// XCD assignment is round-robin on linear block id (round-8: 30 -> 2.5x A re-fetch).
// NOTE: don't trade U-depth for split-K occupancy on the SHIFT convs (round-10:
// U=2 + ksplit4 -> MfmaUtil 40->27%, VALUBusy 39%, +120us).
// MODE 0: conv epilogue relu(bn(acc)) -> bf16, interior rows. NCAT: gc>=nsplit -> {Cb2,bn2}.
//         DUALZ: bz>>1 selects {A2,B2,Cb2,bn2}, bz&1 = batch.
// MODE 3: plain f32 (SPLITK: atomicAdd into zeroed Cf)
// MODE 5: sc: gamma*acc+resid[gr,gc] -> bf16, interior gr
// MODE 6: qkv concat: gc<64 -> QC(+bq), <128 -> KC(+bk), else VC(+bv); compact rows
// MODE 7: head: N=120 -> 3 f32 output planes in d_out (+bias), interior rows; KCAT2 A-concat
struct GArgs {
  const u16 *A, *A2, *B, *B2; u16 *Cb, *Cb2, *Cb3; float* Cf;
  const u16* resid;
  const float *bn, *bn2, *bias, *bias2, *bias3, *gamma, *lambp, *dR, *dC;
  long sA, sB, sC, sres;
  int M, N, KT, ktps, lda, ldb, ldc, Mclamp, Nclamp, nsplit, ksplit, kps;
};

template<int MODE, bool SHIFT, bool NCAT, bool DUALZ, int U, bool SPLITK, bool KCAT2=false>
__global__ __launch_bounds__(256) void k_gemm(GArgs g){
  __shared__ alignas(16) short As[U*4096];
  __shared__ alignas(16) short Bs[U*4096];
  const int bz = blockIdx.z;
  const int sel = DUALZ ? (bz>>1) : 0;
  int bt  = DUALZ ? (bz&1)  : bz;
  int slice = 0;
  if constexpr(SPLITK){ bt = bz / g.ksplit; slice = bz - bt*g.ksplit; }
  const u16* Ab = ((DUALZ && sel) ? g.A2 : g.A) + (long)bt*g.sA;
  const u16* Ab2 = KCAT2 ? (g.A2 + (long)bt*g.sA) : nullptr;
  const u16* Bb = ((DUALZ && sel) ? g.B2 : g.B) + (long)bt*g.sB;
  const int m0 = blockIdx.x*128, n0 = blockIdx.y*128;
  const int tid = threadIdx.x, wid = tid>>6, lane = tid&63;
  const int wr = wid>>1, wc = wid&1;
  const int fr = lane&15, fq = lane>>4;
  const int srow = lane>>2;
  const int swz = ((lane&3) ^ ((lane>>3)&3)) << 3;   // swizzled 8-short slot within 32-short row

  long raB[2], rbB[2];
#pragma unroll
  for(int h=0;h<2;h++){
    long ra = m0 + wid*32 + h*16 + srow;
    if (!SHIFT) ra = (ra > g.Mclamp) ? (long)g.Mclamp : ra;
    raB[h] = ra*(long)g.lda + swz;
    long rb = n0 + wid*32 + h*16 + srow;
    rb = (rb > g.Nclamp) ? (long)g.Nclamp : rb;
    rbB[h] = rb*(long)g.ldb + swz;
  }
  const int ldsOff[2] = { (wid*32)*64, (wid*32+16)*64 };   // byte offsets within one buffer
  const int rswz = (fq ^ ((fr>>1)&3)) << 3;                // read-side slot (same involution)
  const int aRdO = (wr*64+fr)*32 + rswz;                   // shorts, within one buffer
  const int bRdO = (wc*64+fr)*32 + rswz;

  floatx4 acc[4][4];
#pragma unroll
  for(int i=0;i<4;i++)
#pragma unroll
    for(int j=0;j<4;j++)
#pragma unroll
      for(int e=0;e<4;e++) acc[i][j][e]=0.f;

  if constexpr(SHIFT){
    const int KB = g.ktps;
    for(int s=0; s<9; ++s){
      const long aoff = (long)((s/3)*64 + (s-(s/3)*3) - 65)*g.lda; // (ky-1)*64+(kx-1)
      const long boff = (long)s*KB*32;
      for(int kb=0; kb<KB; kb+=U){
        __syncthreads();
#pragma unroll
        for(int u=0;u<U;++u){
          const int ko = (kb+u)*32;
#pragma unroll
          for(int h=0;h<2;h++){
            gll16(Ab + raB[h] + aoff + ko, (char*)As + u*8192 + ldsOff[h]);
            gll16(Bb + rbB[h] + boff + ko, (char*)Bs + u*8192 + ldsOff[h]);
          }
        }
        __syncthreads();
#pragma unroll
        for(int u=0;u<U;++u){
          short8 af[4], bfv[4];
#pragma unroll
          for(int mi=0;mi<4;mi++) af[mi]  = *(const short8*)(As + u*4096 + aRdO + mi*512);
#pragma unroll
          for(int ni=0;ni<4;ni++) bfv[ni] = *(const short8*)(Bs + u*4096 + bRdO + ni*512);
#pragma unroll
          for(int mi=0;mi<4;mi++)
#pragma unroll
            for(int ni=0;ni<4;ni++)
              acc[mi][ni] = __builtin_amdgcn_mfma_f32_16x16x32_bf16(af[mi], bfv[ni], acc[mi][ni], 0,0,0);
        }
      }
    }
  } else {
    int kt0 = 0, ktN = g.KT;
    if constexpr(SPLITK){ kt0 = slice*g.kps; ktN = min(g.KT, kt0+g.kps); }
    for(int kt=kt0; kt<ktN; kt+=U){
      __syncthreads();
#pragma unroll
      for(int u=0;u<U;++u){
        if (kt+u < ktN){
          int ko = kt+u;
          const u16* srcA = Ab;
          if constexpr(KCAT2){ if (ko >= (g.KT>>1)){ srcA = Ab2; ko -= (g.KT>>1); } }
          const int koB = (kt+u)*32;
#pragma unroll
          for(int h=0;h<2;h++){
            gll16(srcA + raB[h] + ko*32, (char*)As + u*8192 + ldsOff[h]);
            gll16(Bb + rbB[h] + koB, (char*)Bs + u*8192 + ldsOff[h]);
          }
        }
      }
      __syncthreads();
#pragma unroll
      for(int u=0;u<U;++u){
        if (kt+u < ktN){
          short8 af[4], bfv[4];
#pragma unroll
          for(int mi=0;mi<4;mi++) af[mi]  = *(const short8*)(As + u*4096 + aRdO + mi*512);
#pragma unroll
          for(int ni=0;ni<4;ni++) bfv[ni] = *(const short8*)(Bs + u*4096 + bRdO + ni*512);
#pragma unroll
          for(int mi=0;mi<4;mi++)
#pragma unroll
            for(int ni=0;ni<4;ni++)
              acc[mi][ni] = __builtin_amdgcn_mfma_f32_16x16x32_bf16(af[mi], bfv[ni], acc[mi][ni], 0,0,0);
        }
      }
    }
  }

  float* Cf = (MODE==3) ? g.Cf + (long)bt*g.sC : nullptr;
  const u16* Rb = (MODE==5) ? g.resid + (long)bt*g.sres : nullptr;
  float gamv=0.f;
  if constexpr(MODE==5) gamv = *g.gamma;

#pragma unroll
  for(int ni=0;ni<4;ni++){
    const int gc = n0 + wc*64 + ni*16 + fr;
    if (gc >= g.N) continue;
    if constexpr(MODE==0){
      const float* bnP = g.bn; u16* CbP = g.Cb; int oc = gc;
      if constexpr(DUALZ){ if (sel){ bnP = g.bn2; CbP = g.Cb2; } }
      if constexpr(NCAT){ if (gc >= g.nsplit){ bnP = g.bn2; CbP = g.Cb2; oc = gc - g.nsplit; } }
      CbP += (long)bt*g.sC;
      const float s_=bnP[oc], bb=bnP[CI+oc], mm=bnP[2*CI+oc], vv=bnP[3*CI+oc];
      const float cA = s_*rsqrtf(vv+1e-5f), cB = bb - cA*mm;
#pragma unroll
      for(int mi=0;mi<4;mi++)
#pragma unroll
        for(int j=0;j<4;j++){
          const int gr = m0 + wr*64 + mi*16 + fq*4 + j;
          if (interior(gr)) CbP[(size_t)gr*g.ldc + oc] = f2b(fmaxf(cA*acc[mi][ni][j]+cB, 0.f));
        }
    } else if constexpr(MODE==6){
      u16* dst; int col, ld; float bs;
      if (gc < 64){ dst = g.Cb  + (long)bt*((long)NPIX*CQ); col=gc;     ld=CQ; bs=g.bias[gc]; }
      else if (gc < 128){ dst = g.Cb2 + (long)bt*((long)NPIX*CQ); col=gc-64; ld=CQ; bs=g.bias2[gc-64]; }
      else { dst = g.Cb3 + (long)bt*((long)NPIX*CI); col=gc-128; ld=CI; bs=g.bias3[gc-128]; }
#pragma unroll
      for(int mi=0;mi<4;mi++)
#pragma unroll
        for(int j=0;j<4;j++){
          const int gr = m0 + wr*64 + mi*16 + fq*4 + j;
          if (interior(gr)) dst[(size_t)compact_of(gr)*ld + col] = f2b(acc[mi][ni][j] + bs);
        }
    } else if constexpr(MODE==3){
#pragma unroll
      for(int mi=0;mi<4;mi++)
#pragma unroll
        for(int j=0;j<4;j++){
          const int gr = m0 + wr*64 + mi*16 + fq*4 + j;
          if (gr < g.M){
            if constexpr(SPLITK) atomicAdd(&Cf[(size_t)gr*g.ldc + gc], acc[mi][ni][j]);
            else Cf[(size_t)gr*g.ldc + gc] = acc[mi][ni][j];
          }
        }
    } else if constexpr(MODE==5){
      u16* CbP = g.Cb + (long)bt*g.sC;
#pragma unroll
      for(int mi=0;mi<4;mi++)
#pragma unroll
        for(int j=0;j<4;j++){
          const int gr = m0 + wr*64 + mi*16 + fq*4 + j;
          if (interior(gr)){ const size_t o=(size_t)gr*g.ldc + gc; CbP[o] = f2b(gamv*acc[mi][ni][j] + b2f(Rb[o])); }
        }
    } else if constexpr(MODE==7){
      size_t hb; int oc; const float* bp;
      if (gc < 40){ hb = 0; oc = gc; bp = g.bias; }
      else if (gc < 80){ hb = 288000; oc = gc-40; bp = g.bias2; }
      else { hb = 576000; oc = gc-80; bp = g.bias3; }
      float* dst = g.Cf + hb + (size_t)bt*144000 + (size_t)oc*3600;
      const float bsv = bp[oc];
#pragma unroll
      for(int mi=0;mi<4;mi++)
#pragma unroll
        for(int j=0;j<4;j++){
          const int gr = m0 + wr*64 + mi*16 + fq*4 + j;
          if (interior(gr)) dst[compact_of(gr)] = acc[mi][ni][j] + bsv;
        }
    }
  }
}

// ---------------- fused energy + softmax -> P bf16 (one batch per launch) ----------------
// 225 blocks x 512 threads: block owns 16 q-rows; 8 waves split the 29 col-tiles.
// Pass-1 scores cached in registers (no recompute); emit via per-wave LDS bounce (coalesced).
__global__ __launch_bounds__(512) void k_esm(const u16* __restrict__ qc, const u16* __restrict__ kc,
    const float* __restrict__ dd, const float* __restrict__ lamp, u16* __restrict__ pb){
  __shared__ float lm[8][16], ll[8][16];
  __shared__ alignas(16) u16 pemit[8][16][128];
  const int tid = threadIdx.x, wave = tid>>6, lane = tid&63;
  const int fr = lane&15, fq = lane>>4;
  const int q0 = blockIdx.x*16;
  const float lam = *lamp;
  const u16* qp = qc + (size_t)(q0+fr)*CQ + fq*8;
  const short8 qa0 = *(const short8*)(qp);
  const short8 qa1 = *(const short8*)(qp + 32);
  float dr[4];
#pragma unroll
  for(int j=0;j<4;j++) dr[j] = dd[q0 + fq*4 + j];
  float m[4], l[4];
#pragma unroll
  for(int j=0;j<4;j++){ m[j] = -3e38f; l[j] = 0.f; }
  float vals[4][8][4];   // cached masked scores, statically indexed (rule #20)

  // pass 1: per-wave online row max + sum, scores cached
#pragma unroll
  for(int tt=0; tt<4; ++tt){
    const int t = wave + tt*8;
    if (t < 29){
      const int n0 = t*128;
      floatx4 s[8]; float dc[8];
#pragma unroll
      for(int ni=0; ni<8; ++ni){
        const int ccol = min(n0 + ni*16 + fr, NPIX-1);
        const u16* kp = kc + (size_t)ccol*CQ + fq*8;
        const short8 b0 = *(const short8*)(kp);
        const short8 b1 = *(const short8*)(kp + 32);
        floatx4 z = {0.f,0.f,0.f,0.f};
        z = __builtin_amdgcn_mfma_f32_16x16x32_bf16(qa0, b0, z, 0,0,0);
        s[ni] = __builtin_amdgcn_mfma_f32_16x16x32_bf16(qa1, b1, z, 0,0,0);
        dc[ni] = dd[ccol];
      }
#pragma unroll
      for(int j=0;j<4;j++){
        float tmax = -3e38f;
#pragma unroll
        for(int ni=0;ni<8;ni++){
          const float td = dr[j] - dc[ni];
          float v = s[ni][j] + lam*td*td;
          if (n0 + ni*16 + fr >= NPIX) v = -3e38f;
          vals[tt][ni][j] = v; tmax = fmaxf(tmax, v);
        }
        tmax = fmaxf(tmax, __shfl_xor(tmax,1,64));
        tmax = fmaxf(tmax, __shfl_xor(tmax,2,64));
        tmax = fmaxf(tmax, __shfl_xor(tmax,4,64));
        tmax = fmaxf(tmax, __shfl_xor(tmax,8,64));
        const float mn = fmaxf(m[j], tmax);
        float ts = 0.f;
#pragma unroll
        for(int ni=0;ni<8;ni++) ts += __expf(vals[tt][ni][j]-mn);
        ts += __shfl_xor(ts,1,64);
        ts += __shfl_xor(ts,2,64);
        ts += __shfl_xor(ts,4,64);
        ts += __shfl_xor(ts,8,64);
        l[j] = l[j]*__expf(m[j]-mn) + ts;
        m[j] = mn;
      }
    }
  }
  if (fr == 0){
#pragma unroll
    for(int j=0;j<4;j++){ lm[wave][fq*4+j] = m[j]; ll[wave][fq*4+j] = l[j]; }
  }
  __syncthreads();
  float M[4], L[4];
#pragma unroll
  for(int j=0;j<4;j++){
    const int row = fq*4 + j;
    float mm = lm[0][row];
#pragma unroll
    for(int w=1;w<8;w++) mm = fmaxf(mm, lm[w][row]);
    float ss = 0.f;
#pragma unroll
    for(int w=0;w<8;w++) ss += ll[w][row]*__expf(lm[w][row]-mm);
    M[j] = mm; L[j] = 1.f/ss;
  }

  // pass 2: normalize cached scores, bounce through per-wave LDS tile, coalesced emit
#pragma unroll
  for(int tt=0; tt<4; ++tt){
    const int t = wave + tt*8;
    if (t < 29){
      const int n0 = t*128;
#pragma unroll
      for(int ni=0;ni<8;ni++)
#pragma unroll
        for(int j=0;j<4;j++)
          pemit[wave][fq*4+j][ni*16+fr] = f2b(__expf(vals[tt][ni][j] - M[j])*L[j]);
      asm volatile("s_waitcnt lgkmcnt(0)" ::: "memory");
#pragma unroll
      for(int it=0; it<4; ++it){
        const int row = it*4 + fq;
        const int c8 = fr*8;
        uint4 v; __builtin_memcpy(&v, &pemit[wave][row][c8], 16);
        *(uint4*)(pb + (size_t)(q0+row)*NK + n0 + c8) = v;
      }
    }
  }
}

// ---------------- zero only guard + ring rows of padded pixel-major tensors ----------------
__global__ __launch_bounds__(256) void k_zring(u16* __restrict__ base, int C, long slabStride){
  const int row = blockIdx.x, slab = blockIdx.y;
  bool z;
  if (row < GUARD || row >= GUARD+PP) z = true;
  else z = !interior(row - GUARD);
  if (!z) return;
  u16* p = base + (size_t)slab*slabStride + (size_t)row*C;
  for (int i = threadIdx.x*8; i < C; i += 256*8){
    uint4 zz = {0,0,0,0};
    *(uint4*)(p + i) = zz;
  }
}

// ---------------- x f32 [B,2048,3600] -> padded pixel-major bf16 [B][4352][2048] ----------------
__global__ __launch_bounds__(256) void k_padx(const float* __restrict__ x, u16* __restrict__ xpm){
  __shared__ alignas(16) u16 t[64][72];
  const int n0 = blockIdx.x*64, c0 = blockIdx.y*64, b = blockIdx.z;
  const float* xb = x + (size_t)b*CIN*NPIX;
  u16* ob = xpm + (size_t)b*(PP+2*GUARD)*CIN + (size_t)GUARD*CIN;
  const int tid = threadIdx.x;
#pragma unroll
  for(int pass=0; pass<2; ++pass){
    const int cl = pass*32 + (tid>>3);
    const int nn = (tid&7)*8;
    const int n = n0 + nn;
    const float* src = xb + (size_t)(c0+cl)*NPIX + n;
    u16 r[8];
    if (n + 7 < NPIX){
      const float4 v0 = *(const float4*)src;
      const float4 v1 = *(const float4*)(src+4);
      r[0]=f2b(v0.x); r[1]=f2b(v0.y); r[2]=f2b(v0.z); r[3]=f2b(v0.w);
      r[4]=f2b(v1.x); r[5]=f2b(v1.y); r[6]=f2b(v1.z); r[7]=f2b(v1.w);
    } else {
#pragma unroll
      for(int j=0;j<8;j++){ const int nj=n+j; r[j] = (nj<NPIX)? f2b(src[j]) : (u16)0; }
    }
    __builtin_memcpy(&t[cl][nn], r, 16);
  }
  __syncthreads();
#pragma unroll
  for(int pass=0; pass<2; ++pass){
    const int nl = pass*32 + (tid>>3);
    const int cc = (tid&7)*8;
    const int n = n0 + nl;
    if (n < NPIX){
      u16 v[8];
#pragma unroll
      for(int j=0;j<8;j++) v[j] = t[cc+j][nl];
      uint4 vv; __builtin_memcpy(&vv, v, 16);
      *(uint4*)(ob + (size_t)pad_of(n)*CIN + c0 + cc) = vv;
    }
  }
}

// ---------------- bf16 [rows, 512] pixel-major -> [512, NK] channel-major (zero tail) ----------------
template<bool PADIN>
__global__ __launch_bounds__(256) void k_to_cm(const u16* __restrict__ in, u16* __restrict__ out,
                                               long sIn, long sOut){
  __shared__ alignas(16) u16 t[64][72];
  const int n0 = blockIdx.x*64, c0 = blockIdx.y*64, b = blockIdx.z;
  const u16* ib = in + (size_t)b*sIn;
  u16* ob = out + (size_t)b*sOut;
  const int tid = threadIdx.x;
#pragma unroll
  for(int pass=0; pass<2; ++pass){
    const int nl = pass*32 + (tid>>3);
    const int cc = (tid&7)*8;
    const int n = n0 + nl;
    uint4 v = {0,0,0,0};
    if (n < NPIX){
      const int r = PADIN ? pad_of(n) : n;
      v = *(const uint4*)(ib + (size_t)r*CI + c0 + cc);
    }
    *(uint4*)&t[nl][cc] = v;
  }
  __syncthreads();
#pragma unroll
  for(int pass=0; pass<2; ++pass){
    const int cl = pass*32 + (tid>>3);
    const int nn = (tid&7)*8;
    const int n = n0 + nn;
    if (n < NK){
      u16 v[8];
#pragma unroll
      for(int j=0;j<8;j++) v[j] = t[nn+j][cl];
      uint4 vv; __builtin_memcpy(&vv, v, 16);
      *(uint4*)(ob + (size_t)(c0+cl)*NK + n) = vv;
    }
  }
}

// ---------------- dual weight transform: w f32 [O,Kc,3,3] -> Wt bf16 [O, 9*Kc] ----------------
__global__ __launch_bounds__(256) void k_wt2(const float* __restrict__ wA, const float* __restrict__ wB,
                                             u16* __restrict__ wtA, u16* __restrict__ wtB, int Kc){
  const float* w = blockIdx.y ? wB : wA;
  u16* wt = blockIdx.y ? wtB : wtA;
  const int idx = blockIdx.x*256 + threadIdx.x;
  const int o = idx / Kc, i = idx - o*Kc;
  u16 v[9];
#pragma unroll
  for(int s=0;s<9;s++) v[s] = f2b(w[(size_t)idx*9 + s]);
#pragma unroll
  for(int s=0;s<9;s++) wt[(size_t)o*9*Kc + (size_t)s*Kc + i] = v[s];
}

// ---------------- f32 -> bf16, three concatenated sources ----------------
__global__ __launch_bounds__(256) void k_cvt3(const float* __restrict__ a, int na,
                                              const float* __restrict__ b, int nb,
                                              const float* __restrict__ c, int nc,
                                              u16* __restrict__ dst){
  const int i = blockIdx.x*256 + threadIdx.x;
  float v;
  if (i < na) v = a[i];
  else if (i < na+nb) v = b[i-na];
  else if (i < na+nb+nc) v = c[i-na-nb];
  else return;
  dst[i] = f2b(v);
}

// ---------------- head weight concat: WH[120][1024] bf16 ----------------
__global__ __launch_bounds__(256) void k_whead(const float* __restrict__ w6, const float* __restrict__ w7,
                                               const float* __restrict__ w8, u16* __restrict__ wh){
  const int idx = blockIdx.x*256 + threadIdx.x;   // 120*1024
  const int r = idx >> 10, k = idx & 1023;
  float v = 0.f;
  if (r < 40) v = w8[r*512 + (k & 511)];
  else if (r < 80){ if (k < 512) v = w6[(r-40)*512 + k]; }
  else { if (k >= 512) v = w7[(r-80)*512 + (k-512)]; }
  wh[idx] = f2b(v);
}

// ---------------- channel softmax ----------------
__global__ __launch_bounds__(256) void k_csoftmax(const float* __restrict__ cen, u16* __restrict__ catt){
  const int c = blockIdx.x, b = blockIdx.y, tid = threadIdx.x;
  const float* e = cen + ((size_t)b*CI + c)*CI;
  u16* o = catt + ((size_t)b*CI + c)*CI;
  __shared__ float red[8];
  const float a0 = e[tid], a1 = e[tid+256];
  float lmin = fminf(a0,a1);
  lmin = wred_min(lmin);
  if((tid&63)==0) red[tid>>6]=lmin;
  __syncthreads();
  const float m0 = fminf(fminf(red[0],red[1]),fminf(red[2],red[3]));
  const float x0 = __expf(m0-a0), x1 = __expf(m0-a1);
  float ls = x0+x1;
  ls = wred_sum(ls);
  if((tid&63)==0) red[4+(tid>>6)]=ls;
  __syncthreads();
  const float inv = 1.f/(red[4]+red[5]+red[6]+red[7]);
  o[tid] = f2b(x0*inv); o[tid+256] = f2b(x1*inv);
}

// ---------------- PV epilogue: SAPM[pad(n),c] = gamma*SAF[n,c] + F1[pad(n),c] ----------------
__global__ __launch_bounds__(256) void k_pv_ep(const float* __restrict__ saf, const u16* __restrict__ f1,
                                               u16* __restrict__ sapm, const float* __restrict__ gamma){
  const int idx = blockIdx.x*256 + threadIdx.x;   // 230400 threads, 8 elems each
  const int n = idx >> 6, c = (idx & 63) * 8;
  const float gam = *gamma;
  const int p = pad_of(n);
  const float4 v0 = *(const float4*)(saf + (size_t)n*CI + c);
  const float4 v1 = *(const float4*)(saf + (size_t)n*CI + c + 4);
  const uint4 rv = *(const uint4*)(f1 + (size_t)p*CI + c);
  const u16* rp = (const u16*)&rv;
  u16 o[8];
  o[0]=f2b(gam*v0.x + b2f(rp[0])); o[1]=f2b(gam*v0.y + b2f(rp[1]));
  o[2]=f2b(gam*v0.z + b2f(rp[2])); o[3]=f2b(gam*v0.w + b2f(rp[3]));
  o[4]=f2b(gam*v1.x + b2f(rp[4])); o[5]=f2b(gam*v1.y + b2f(rp[5]));
  o[6]=f2b(gam*v1.z + b2f(rp[6])); o[7]=f2b(gam*v1.w + b2f(rp[7]));
  uint4 ov; __builtin_memcpy(&ov, o, 16);
  *(uint4*)(sapm + (size_t)p*CI + c) = ov;
}

// ---------------- launch ----------------
extern "C" void kernel_launch(void* const* d_in, const int* in_sizes, int n_in,
                              void* d_out, int out_size, void* d_ws, size_t ws_size,
                              hipStream_t stream){
  (void)in_sizes; (void)n_in; (void)out_size;
  if (ws_size < WS_NEED) return;

  const float* x    = (const float*)d_in[0];
  const float* dd   = (const float*)d_in[1];
  const float* w_s0 = (const float*)d_in[2];
  const float* bn_s0= (const float*)d_in[3];
  const float* wq   = (const float*)d_in[4];
  const float* bq   = (const float*)d_in[5];
  const float* wk   = (const float*)d_in[6];
  const float* bk   = (const float*)d_in[7];
  const float* wv   = (const float*)d_in[8];
  const float* bv   = (const float*)d_in[9];
  const float* gsa  = (const float*)d_in[10];
  const float* lam  = (const float*)d_in[11];
  const float* w_s1 = (const float*)d_in[12];
  const float* bn_s1= (const float*)d_in[13];
  const float* w6   = (const float*)d_in[14];
  const float* b6   = (const float*)d_in[15];
  const float* w_c0 = (const float*)d_in[16];
  const float* bn_c0= (const float*)d_in[17];
  const float* gsc  = (const float*)d_in[18];
  const float* w_c1 = (const float*)d_in[19];
  const float* bn_c1= (const float*)d_in[20];
  const float* w7   = (const float*)d_in[21];
  const float* b7   = (const float*)d_in[22];
  const float* w8   = (const float*)d_in[23];
  const float* b8   = (const float*)d_in[24];

  char* W = (char*)d_ws;
  u16*   XPM   = (u16*)(W + OFF_XPM);
  float* SAF   = (float*)(W + OFF_SAF);
  u16*   PB    = (u16*)(W + OFF_PBUF);
  u16*   SACONV= (u16*)(W + OFF_SACONV);
  u16*   SCCONV= (u16*)(W + OFF_SCCONV);
  u16*   F1    = (u16*)(W + OFF_FEAT1);
  u16*   F2    = (u16*)(W + OFF_FEAT2);
  u16*   SAPM  = (u16*)(W + OFF_SAPM);
  u16*   SCPM  = (u16*)(W + OFF_SCPM);
  u16*   WTT   = (u16*)(W + OFF_W);
  u16*   WQB   = (u16*)(W + OFF_WQB);
  u16*   QC    = (u16*)(W + OFF_QC);
  u16*   KC    = (u16*)(W + OFF_KC);
  u16*   VC    = (u16*)(W + OFF_VC);
  u16*   WT1   = (u16*)(W + OFF_WT1);
  u16*   WT2   = (u16*)(W + OFF_WT2);
  u16*   WH    = (u16*)(W + OFF_WH);
  u16*   VCM   = (u16*)(W + OFF_VCM);
  u16*   F2CM  = VCM;                     // time-shared
  float* CEN   = (float*)(W + OFF_CEN);
  u16*   CATT  = (u16*)(W + OFF_CATT);
  float* OUT   = (float*)d_out;

  // zero only guard+ring rows (interiors are fully overwritten)
  k_zring<<<dim3(PP+2*GUARD, 2),256,0,stream>>>(XPM,  CIN, (long)(PP+2*GUARD)*CIN);
  k_zring<<<dim3(PP+2*GUARD, 4),256,0,stream>>>(SAPM, CI,  (long)(PP+2*GUARD)*CI);  // SAPM+SCPM contiguous

  k_padx<<<dim3(57,32,2),256,0,stream>>>(x, XPM);

  // conv s0 + c0 fused (N-concat), U=4 (BK=128); grid.x=32 (multiple of 8 — XCD A-sharing)
  k_wt2<<<dim3((512*2048)/256, 2),256,0,stream>>>(w_s0, w_c0, WTT, WTT + (size_t)512*9*2048, 2048);
  GArgs a{};
  a.A = XPM + (size_t)GUARD*CIN; a.B = WTT; a.Cb = F1; a.Cb2 = F2;
  a.bn = bn_s0; a.bn2 = bn_c0;
  a.sA = (long)(PP+2*GUARD)*CIN; a.sB = 0; a.sC = (long)PP*CI;
  a.M = PP; a.N = 1024; a.nsplit = 512; a.KT = 576; a.ktps = 64;
  a.lda = CIN; a.ldb = 9*2048; a.ldc = CI; a.Mclamp = PP-1; a.Nclamp = 1023;
  k_gemm<0,true,true,false,4,false><<<dim3(32,8,2),256,0,stream>>>(a);

  // bf16 copies of 1x1 weights (concat [wq;wk;wv] = 640x512), one launch
  k_cvt3<<<dim3((64*512+64*512+512*512)/256),256,0,stream>>>(wq, 64*512, wk, 64*512, wv, 512*512, WQB);

  // q,k,v in one GEMM (N=640), U=4
  GArgs q{};
  q.A = F1; q.sA = (long)PP*CI; q.lda = CI;
  q.M = PP; q.Mclamp = PP-1; q.KT = 16; q.ktps = 16;
  q.B = WQB; q.sB = 0; q.ldb = CI; q.N = 640; q.Nclamp = 639;
  q.Cb = QC; q.Cb2 = KC; q.Cb3 = VC; q.bias = bq; q.bias2 = bk; q.bias3 = bv;
  k_gemm<6,false,false,false,4,false><<<dim3(32,5,2),256,0,stream>>>(q);

  k_to_cm<false><<<dim3(NK/64, CI/64, 2),256,0,stream>>>(VC, VCM, (long)NPIX*CI, (long)CI*NK);

  // position attention, per batch: fused energy+softmax -> PV(split-K 4) -> epilogue
  for(int bb=0; bb<2; ++bb){
    k_esm<<<dim3(225),512,0,stream>>>(QC + (size_t)bb*NPIX*CQ, KC + (size_t)bb*NPIX*CQ,
                                      dd + (size_t)bb*NPIX, lam, PB);
    hipMemsetAsync(SAF, 0, (size_t)NPIX*CI*4, stream);
    GArgs p{};
    p.A = PB; p.B = VCM + (size_t)bb*CI*NK;
    p.Cf = SAF;
    p.M = NPIX; p.N = CI; p.KT = NK/32; p.ktps = NK/32;
    p.lda = NK; p.ldb = NK; p.ldc = CI; p.sC = 0;
    p.Mclamp = NPIX-1; p.Nclamp = CI-1;
    p.ksplit = 4; p.kps = NK/128;
    k_gemm<3,false,false,false,4,true><<<dim3(29, 4, 4),256,0,stream>>>(p);
    k_pv_ep<<<dim3(NPIX*CI/8/256),256,0,stream>>>(SAF, F1 + (size_t)bb*PP*CI,
                                                  SAPM + (size_t)bb*(PP+2*GUARD)*CI + (size_t)GUARD*CI, gsa);
  }

  // channel attention: Gram with split-K atomics (U=4)
  k_to_cm<true><<<dim3(NK/64, CI/64, 2),256,0,stream>>>(F2, F2CM, (long)PP*CI, (long)CI*NK);
  hipMemsetAsync(CEN, 0, (size_t)2*CI*CI*4, stream);
  GArgs c{};
  c.A = F2CM; c.B = F2CM; c.Cf = CEN;
  c.sA = (long)CI*NK; c.sB = (long)CI*NK; c.sC = (long)CI*CI;
  c.M = CI; c.N = CI; c.KT = NK/32; c.ktps = NK/32;
  c.lda = NK; c.ldb = NK; c.ldc = CI; c.Mclamp = CI-1; c.Nclamp = CI-1;
  c.ksplit = 8; c.kps = (NK/32 + 7)/8;
  k_gemm<3,false,false,false,4,true><<<dim3(4, 4, 16),256,0,stream>>>(c);
  k_csoftmax<<<dim3(CI,2),256,0,stream>>>(CEN, CATT);
  GArgs s{};
  s.A = F2; s.B = CATT;
  s.Cb = SCPM + (size_t)GUARD*CI;
  s.resid = F2; s.gamma = gsc;
  s.sA = (long)PP*CI; s.sB = (long)CI*CI; s.sC = (long)(PP+2*GUARD)*CI; s.sres = (long)PP*CI;
  s.M = PP; s.N = CI; s.KT = 16; s.ktps = 16;
  s.lda = CI; s.ldb = CI; s.ldc = CI; s.Mclamp = PP-1; s.Nclamp = CI-1;
  k_gemm<5,false,false,false,4,false><<<dim3(32, 4, 2),256,0,stream>>>(s);

  // post convs s1 + c1 fused (DUALZ), U=4
  k_wt2<<<dim3((512*512)/256, 2),256,0,stream>>>(w_s1, w_c1, WT1, WT2, 512);
  k_whead<<<dim3(120*1024/256),256,0,stream>>>(w6, w7, w8, WH);
  GArgs t{};
  t.A = SAPM + (size_t)GUARD*CI; t.A2 = SCPM + (size_t)GUARD*CI;
  t.B = WT1; t.B2 = WT2;
  t.Cb = SACONV; t.Cb2 = SCCONV; t.bn = bn_s1; t.bn2 = bn_c1;
  t.sA = (long)(PP+2*GUARD)*CI; t.sB = 0; t.sC = (long)PP*CI;
  t.M = PP; t.N = CI; t.KT = 144; t.ktps = 16;
  t.lda = CI; t.ldb = 9*512; t.ldc = CI; t.Mclamp = PP-1; t.Nclamp = CI-1;
  k_gemm<0,true,false,true,4,false><<<dim3(32,4,4),256,0,stream>>>(t);

  // fused head GEMM: A=[SACONV|SCCONV] (K=1024), B=WH (N=120), f32 out + bias
  GArgs h{};
  h.A = SACONV; h.A2 = SCCONV; h.B = WH; h.Cf = OUT;
  h.bias = b8; h.bias2 = b6; h.bias3 = b7;
  h.sA = (long)PP*CI; h.sB = 0; h.sC = 0;
  h.M = PP; h.N = 120; h.KT = 32; h.ktps = 32;
  h.lda = CI; h.ldb = 1024; h.ldc = 0; h.Mclamp = PP-1; h.Nclamp = 119;
  k_gemm<7,false,false,false,4,false,true><<<dim3(32,1,2),256,0,stream>>>(h);
}

// Round 13
// 718.863 us; speedup vs baseline: 1.2068x; 1.0118x over previous
//
#include <hip/hip_runtime.h>
#include <stdint.h>

#define DI __device__ __forceinline__

typedef unsigned short u16;
typedef unsigned int u32;
typedef __attribute__((ext_vector_type(8))) short short8;
typedef __attribute__((ext_vector_type(4))) float floatx4;

// ---------------- geometry ----------------
constexpr int NPIX = 3600;   // 60*60
constexpr int NK   = 3712;   // 3600 padded to multiple of 128 (zero tail)
constexpr int PP   = 4096;   // 64*64 padded pixel grid (image at [2..61]^2)
constexpr int GUARD= 128;    // guard rows on padded-pixel tensors (shifted reads)
constexpr int CIN  = 2048, CI = 512, CQ = 64;

// ---------------- ws layout (bytes) ----------------
// R1 time-shared: XPM (convs) -> SAF/PBUF (attention) -> SACONV/SCCONV (tail)
constexpr size_t OFF_XPM    = 0;                       // 2*4352*2048*2 = 35,651,584
constexpr size_t OFF_SAF    = 0;                       // 3600*512*4 = 7,372,800
constexpr size_t OFF_PBUF   = 14745600;                // 3600*3712*2 = 26,726,400 -> ends 41,472,000
constexpr size_t OFF_SACONV = 0;                       // 2*4096*512*2 = 8,388,608
constexpr size_t OFF_SCCONV = 8388608;
constexpr size_t R1_END     = 42812416;
constexpr size_t OFF_FEAT1  = R1_END;                  // 8,388,608
constexpr size_t OFF_FEAT2  = OFF_FEAT1 + 8388608;
constexpr size_t OFF_SAPM   = OFF_FEAT2 + 8388608;     // 8,912,896
constexpr size_t OFF_SCPM   = OFF_SAPM + 8912896;
constexpr size_t OFF_W      = OFF_SCPM + 8912896;      // big region, 37,748,736 (WTT 1024x18432)
// inside W (time-shared with WTT / each other). CAUTION: CEN/WH/WT1/WT2 alias the
// WTT span — they may only be written AFTER s0c0 consumes WTT (round-12 bug).
constexpr size_t OFF_WQB = OFF_W;                      // 640*512*2 concat
constexpr size_t OFF_QC  = OFF_W + 655360;             // 2*3600*64*2
constexpr size_t OFF_KC  = OFF_W + 1576960;
constexpr size_t OFF_VC  = OFF_W + 2498560;            // 2*3600*512*2 -> ends +9,871,360
constexpr size_t OFF_WT1 = OFF_W;                      // 512*4608*2 (s1) — QC/KC/VC dead by then
constexpr size_t OFF_WT2 = OFF_W + 4718592;            // 512*4608*2 (c1)
constexpr size_t OFF_VCM = OFF_W + 9871360;            // 2*512*3712*2 = 7,602,176 (shared w/ F2CM)
constexpr size_t OFF_CEN = OFF_W + 17473536;           // 2*512*512*4 = 2,097,152
constexpr size_t OFF_CATT= OFF_W + 19570688;           // 2*512*512*2 = 1,048,576 -> ends +20,619,264
constexpr size_t OFF_WH  = OFF_W + 20619264;           // 120*1024*2 = 245,760
constexpr size_t WS_NEED = OFF_W + 37748736;           // 115,164,160 (proven)

// ---------------- helpers ----------------
DI float b2f(u16 s){ u32 u = ((u32)s)<<16; float f; __builtin_memcpy(&f,&u,4); return f; }
DI u16 f2b(float f){ u32 u; __builtin_memcpy(&u,&f,4); u32 r=(u+0x7fffu+((u>>16)&1u))>>16; return (u16)r; }
DI int pad_of(int n){ int y=n/60, x=n-y*60; return ((y+2)<<6)+x+2; }
DI bool interior(int p){ int py=p>>6, px=p&63; return (py>=2)&&(py<62)&&(px>=2)&&(px<62); }
DI int compact_of(int p){ return ((p>>6)-2)*60 + (p&63) - 2; }
DI void gll16(const void* g, void* l){
  __builtin_amdgcn_global_load_lds((const __attribute__((address_space(1))) void*)g,
                                   (__attribute__((address_space(3))) void*)l, 16, 0, 0);
}
DI float wred_min(float v){
#pragma unroll
  for(int m=32;m;m>>=1) v=fminf(v,__shfl_xor(v,m,64));
  return v;
}
DI float wred_sum(float v){
#pragma unroll
  for(int m=32;m;m>>=1) v+=__shfl_xor(v,m,64);
  return v;
}

// ---------------- NT GEMM: C[M,N] = sum_k A[m,k]*B[n,k] (A,B bf16) ----------------
// NOTE: gridDim.x MUST be a multiple of 8 (or share no A-panels across y/z):
// XCD assignment is round-robin on linear block id (round-8: 30 -> 2.5x A re-fetch).
// NOTE: don't trade U-depth for split-K occupancy on the SHIFT convs (round-10:
// U=2 + ksplit4 -> MfmaUtil 40->27%, VALUBusy 39%, +120us).
// MODE 0: conv epilogue relu(bn(acc)) -> bf16, interior rows. NCAT: gc>=nsplit -> {Cb2,bn2}.
//         DUALZ: bz>>1 selects {A2,B2,Cb2,bn2}, bz&1 = batch.
// MODE 3: plain f32 (SPLITK: atomicAdd into zeroed Cf)
// MODE 5: sc: gamma*acc+resid[gr,gc] -> bf16, interior gr
// MODE 6: qkv concat: gc<64 -> QC(+bq), <128 -> KC(+bk), else VC(+bv); compact rows
// MODE 7: head: N=120 -> 3 f32 output planes in d_out (+bias), interior rows; KCAT2 A-concat
struct GArgs {
  const u16 *A, *A2, *B, *B2; u16 *Cb, *Cb2, *Cb3; float* Cf;
  const u16* resid;
  const float *bn, *bn2, *bias, *bias2, *bias3, *gamma, *lambp, *dR, *dC;
  long sA, sB, sC, sres;
  int M, N, KT, ktps, lda, ldb, ldc, Mclamp, Nclamp, nsplit, ksplit, kps;
};

template<int MODE, bool SHIFT, bool NCAT, bool DUALZ, int U, bool SPLITK, bool KCAT2=false>
__global__ __launch_bounds__(256) void k_gemm(GArgs g){
  __shared__ alignas(16) short As[U*4096];
  __shared__ alignas(16) short Bs[U*4096];
  const int bz = blockIdx.z;
  const int sel = DUALZ ? (bz>>1) : 0;
  int bt  = DUALZ ? (bz&1)  : bz;
  int slice = 0;
  if constexpr(SPLITK){ bt = bz / g.ksplit; slice = bz - bt*g.ksplit; }
  const u16* Ab = ((DUALZ && sel) ? g.A2 : g.A) + (long)bt*g.sA;
  const u16* Ab2 = KCAT2 ? (g.A2 + (long)bt*g.sA) : nullptr;
  const u16* Bb = ((DUALZ && sel) ? g.B2 : g.B) + (long)bt*g.sB;
  const int m0 = blockIdx.x*128, n0 = blockIdx.y*128;
  const int tid = threadIdx.x, wid = tid>>6, lane = tid&63;
  const int wr = wid>>1, wc = wid&1;
  const int fr = lane&15, fq = lane>>4;
  const int srow = lane>>2;
  const int swz = ((lane&3) ^ ((lane>>3)&3)) << 3;   // swizzled 8-short slot within 32-short row

  long raB[2], rbB[2];
#pragma unroll
  for(int h=0;h<2;h++){
    long ra = m0 + wid*32 + h*16 + srow;
    if (!SHIFT) ra = (ra > g.Mclamp) ? (long)g.Mclamp : ra;
    raB[h] = ra*(long)g.lda + swz;
    long rb = n0 + wid*32 + h*16 + srow;
    rb = (rb > g.Nclamp) ? (long)g.Nclamp : rb;
    rbB[h] = rb*(long)g.ldb + swz;
  }
  const int ldsOff[2] = { (wid*32)*64, (wid*32+16)*64 };   // byte offsets within one buffer
  const int rswz = (fq ^ ((fr>>1)&3)) << 3;                // read-side slot (same involution)
  const int aRdO = (wr*64+fr)*32 + rswz;                   // shorts, within one buffer
  const int bRdO = (wc*64+fr)*32 + rswz;

  floatx4 acc[4][4];
#pragma unroll
  for(int i=0;i<4;i++)
#pragma unroll
    for(int j=0;j<4;j++)
#pragma unroll
      for(int e=0;e<4;e++) acc[i][j][e]=0.f;

  if constexpr(SHIFT){
    const int KB = g.ktps;
    for(int s=0; s<9; ++s){
      const long aoff = (long)((s/3)*64 + (s-(s/3)*3) - 65)*g.lda; // (ky-1)*64+(kx-1)
      const long boff = (long)s*KB*32;
      for(int kb=0; kb<KB; kb+=U){
        __syncthreads();
#pragma unroll
        for(int u=0;u<U;++u){
          const int ko = (kb+u)*32;
#pragma unroll
          for(int h=0;h<2;h++){
            gll16(Ab + raB[h] + aoff + ko, (char*)As + u*8192 + ldsOff[h]);
            gll16(Bb + rbB[h] + boff + ko, (char*)Bs + u*8192 + ldsOff[h]);
          }
        }
        __syncthreads();
#pragma unroll
        for(int u=0;u<U;++u){
          short8 af[4], bfv[4];
#pragma unroll
          for(int mi=0;mi<4;mi++) af[mi]  = *(const short8*)(As + u*4096 + aRdO + mi*512);
#pragma unroll
          for(int ni=0;ni<4;ni++) bfv[ni] = *(const short8*)(Bs + u*4096 + bRdO + ni*512);
#pragma unroll
          for(int mi=0;mi<4;mi++)
#pragma unroll
            for(int ni=0;ni<4;ni++)
              acc[mi][ni] = __builtin_amdgcn_mfma_f32_16x16x32_bf16(af[mi], bfv[ni], acc[mi][ni], 0,0,0);
        }
      }
    }
  } else {
    int kt0 = 0, ktN = g.KT;
    if constexpr(SPLITK){ kt0 = slice*g.kps; ktN = min(g.KT, kt0+g.kps); }
    for(int kt=kt0; kt<ktN; kt+=U){
      __syncthreads();
#pragma unroll
      for(int u=0;u<U;++u){
        if (kt+u < ktN){
          int ko = kt+u;
          const u16* srcA = Ab;
          if constexpr(KCAT2){ if (ko >= (g.KT>>1)){ srcA = Ab2; ko -= (g.KT>>1); } }
          const int koB = (kt+u)*32;
#pragma unroll
          for(int h=0;h<2;h++){
            gll16(srcA + raB[h] + ko*32, (char*)As + u*8192 + ldsOff[h]);
            gll16(Bb + rbB[h] + koB, (char*)Bs + u*8192 + ldsOff[h]);
          }
        }
      }
      __syncthreads();
#pragma unroll
      for(int u=0;u<U;++u){
        if (kt+u < ktN){
          short8 af[4], bfv[4];
#pragma unroll
          for(int mi=0;mi<4;mi++) af[mi]  = *(const short8*)(As + u*4096 + aRdO + mi*512);
#pragma unroll
          for(int ni=0;ni<4;ni++) bfv[ni] = *(const short8*)(Bs + u*4096 + bRdO + ni*512);
#pragma unroll
          for(int mi=0;mi<4;mi++)
#pragma unroll
            for(int ni=0;ni<4;ni++)
              acc[mi][ni] = __builtin_amdgcn_mfma_f32_16x16x32_bf16(af[mi], bfv[ni], acc[mi][ni], 0,0,0);
        }
      }
    }
  }

  float* Cf = (MODE==3) ? g.Cf + (long)bt*g.sC : nullptr;
  const u16* Rb = (MODE==5) ? g.resid + (long)bt*g.sres : nullptr;
  float gamv=0.f;
  if constexpr(MODE==5) gamv = *g.gamma;

#pragma unroll
  for(int ni=0;ni<4;ni++){
    const int gc = n0 + wc*64 + ni*16 + fr;
    if (gc >= g.N) continue;
    if constexpr(MODE==0){
      const float* bnP = g.bn; u16* CbP = g.Cb; int oc = gc;
      if constexpr(DUALZ){ if (sel){ bnP = g.bn2; CbP = g.Cb2; } }
      if constexpr(NCAT){ if (gc >= g.nsplit){ bnP = g.bn2; CbP = g.Cb2; oc = gc - g.nsplit; } }
      CbP += (long)bt*g.sC;
      const float s_=bnP[oc], bb=bnP[CI+oc], mm=bnP[2*CI+oc], vv=bnP[3*CI+oc];
      const float cA = s_*rsqrtf(vv+1e-5f), cB = bb - cA*mm;
#pragma unroll
      for(int mi=0;mi<4;mi++)
#pragma unroll
        for(int j=0;j<4;j++){
          const int gr = m0 + wr*64 + mi*16 + fq*4 + j;
          if (interior(gr)) CbP[(size_t)gr*g.ldc + oc] = f2b(fmaxf(cA*acc[mi][ni][j]+cB, 0.f));
        }
    } else if constexpr(MODE==6){
      u16* dst; int col, ld; float bs;
      if (gc < 64){ dst = g.Cb  + (long)bt*((long)NPIX*CQ); col=gc;     ld=CQ; bs=g.bias[gc]; }
      else if (gc < 128){ dst = g.Cb2 + (long)bt*((long)NPIX*CQ); col=gc-64; ld=CQ; bs=g.bias2[gc-64]; }
      else { dst = g.Cb3 + (long)bt*((long)NPIX*CI); col=gc-128; ld=CI; bs=g.bias3[gc-128]; }
#pragma unroll
      for(int mi=0;mi<4;mi++)
#pragma unroll
        for(int j=0;j<4;j++){
          const int gr = m0 + wr*64 + mi*16 + fq*4 + j;
          if (interior(gr)) dst[(size_t)compact_of(gr)*ld + col] = f2b(acc[mi][ni][j] + bs);
        }
    } else if constexpr(MODE==3){
#pragma unroll
      for(int mi=0;mi<4;mi++)
#pragma unroll
        for(int j=0;j<4;j++){
          const int gr = m0 + wr*64 + mi*16 + fq*4 + j;
          if (gr < g.M){
            if constexpr(SPLITK) atomicAdd(&Cf[(size_t)gr*g.ldc + gc], acc[mi][ni][j]);
            else Cf[(size_t)gr*g.ldc + gc] = acc[mi][ni][j];
          }
        }
    } else if constexpr(MODE==5){
      u16* CbP = g.Cb + (long)bt*g.sC;
#pragma unroll
      for(int mi=0;mi<4;mi++)
#pragma unroll
        for(int j=0;j<4;j++){
          const int gr = m0 + wr*64 + mi*16 + fq*4 + j;
          if (interior(gr)){ const size_t o=(size_t)gr*g.ldc + gc; CbP[o] = f2b(gamv*acc[mi][ni][j] + b2f(Rb[o])); }
        }
    } else if constexpr(MODE==7){
      size_t hb; int oc; const float* bp;
      if (gc < 40){ hb = 0; oc = gc; bp = g.bias; }
      else if (gc < 80){ hb = 288000; oc = gc-40; bp = g.bias2; }
      else { hb = 576000; oc = gc-80; bp = g.bias3; }
      float* dst = g.Cf + hb + (size_t)bt*144000 + (size_t)oc*3600;
      const float bsv = bp[oc];
#pragma unroll
      for(int mi=0;mi<4;mi++)
#pragma unroll
        for(int j=0;j<4;j++){
          const int gr = m0 + wr*64 + mi*16 + fq*4 + j;
          if (interior(gr)) dst[compact_of(gr)] = acc[mi][ni][j] + bsv;
        }
    }
  }
}

// ---------------- fused energy + softmax -> P bf16 (one batch per launch) ----------------
// 225 blocks x 512 threads: block owns 16 q-rows; 8 waves split the 29 col-tiles.
// Pass-1 scores cached in registers (no recompute); emit via per-wave LDS bounce (coalesced).
__global__ __launch_bounds__(512) void k_esm(const u16* __restrict__ qc, const u16* __restrict__ kc,
    const float* __restrict__ dd, const float* __restrict__ lamp, u16* __restrict__ pb){
  __shared__ float lm[8][16], ll[8][16];
  __shared__ alignas(16) u16 pemit[8][16][128];
  const int tid = threadIdx.x, wave = tid>>6, lane = tid&63;
  const int fr = lane&15, fq = lane>>4;
  const int q0 = blockIdx.x*16;
  const float lam = *lamp;
  const u16* qp = qc + (size_t)(q0+fr)*CQ + fq*8;
  const short8 qa0 = *(const short8*)(qp);
  const short8 qa1 = *(const short8*)(qp + 32);
  float dr[4];
#pragma unroll
  for(int j=0;j<4;j++) dr[j] = dd[q0 + fq*4 + j];
  float m[4], l[4];
#pragma unroll
  for(int j=0;j<4;j++){ m[j] = -3e38f; l[j] = 0.f; }
  float vals[4][8][4];   // cached masked scores, statically indexed (rule #20)

  // pass 1: per-wave online row max + sum, scores cached
#pragma unroll
  for(int tt=0; tt<4; ++tt){
    const int t = wave + tt*8;
    if (t < 29){
      const int n0 = t*128;
      floatx4 s[8]; float dc[8];
#pragma unroll
      for(int ni=0; ni<8; ++ni){
        const int ccol = min(n0 + ni*16 + fr, NPIX-1);
        const u16* kp = kc + (size_t)ccol*CQ + fq*8;
        const short8 b0 = *(const short8*)(kp);
        const short8 b1 = *(const short8*)(kp + 32);
        floatx4 z = {0.f,0.f,0.f,0.f};
        z = __builtin_amdgcn_mfma_f32_16x16x32_bf16(qa0, b0, z, 0,0,0);
        s[ni] = __builtin_amdgcn_mfma_f32_16x16x32_bf16(qa1, b1, z, 0,0,0);
        dc[ni] = dd[ccol];
      }
#pragma unroll
      for(int j=0;j<4;j++){
        float tmax = -3e38f;
#pragma unroll
        for(int ni=0;ni<8;ni++){
          const float td = dr[j] - dc[ni];
          float v = s[ni][j] + lam*td*td;
          if (n0 + ni*16 + fr >= NPIX) v = -3e38f;
          vals[tt][ni][j] = v; tmax = fmaxf(tmax, v);
        }
        tmax = fmaxf(tmax, __shfl_xor(tmax,1,64));
        tmax = fmaxf(tmax, __shfl_xor(tmax,2,64));
        tmax = fmaxf(tmax, __shfl_xor(tmax,4,64));
        tmax = fmaxf(tmax, __shfl_xor(tmax,8,64));
        const float mn = fmaxf(m[j], tmax);
        float ts = 0.f;
#pragma unroll
        for(int ni=0;ni<8;ni++) ts += __expf(vals[tt][ni][j]-mn);
        ts += __shfl_xor(ts,1,64);
        ts += __shfl_xor(ts,2,64);
        ts += __shfl_xor(ts,4,64);
        ts += __shfl_xor(ts,8,64);
        l[j] = l[j]*__expf(m[j]-mn) + ts;
        m[j] = mn;
      }
    }
  }
  if (fr == 0){
#pragma unroll
    for(int j=0;j<4;j++){ lm[wave][fq*4+j] = m[j]; ll[wave][fq*4+j] = l[j]; }
  }
  __syncthreads();
  float M[4], L[4];
#pragma unroll
  for(int j=0;j<4;j++){
    const int row = fq*4 + j;
    float mm = lm[0][row];
#pragma unroll
    for(int w=1;w<8;w++) mm = fmaxf(mm, lm[w][row]);
    float ss = 0.f;
#pragma unroll
    for(int w=0;w<8;w++) ss += ll[w][row]*__expf(lm[w][row]-mm);
    M[j] = mm; L[j] = 1.f/ss;
  }

  // pass 2: normalize cached scores, bounce through per-wave LDS tile, coalesced emit
#pragma unroll
  for(int tt=0; tt<4; ++tt){
    const int t = wave + tt*8;
    if (t < 29){
      const int n0 = t*128;
#pragma unroll
      for(int ni=0;ni<8;ni++)
#pragma unroll
        for(int j=0;j<4;j++)
          pemit[wave][fq*4+j][ni*16+fr] = f2b(__expf(vals[tt][ni][j] - M[j])*L[j]);
      asm volatile("s_waitcnt lgkmcnt(0)" ::: "memory");
#pragma unroll
      for(int it=0; it<4; ++it){
        const int row = it*4 + fq;
        const int c8 = fr*8;
        uint4 v; __builtin_memcpy(&v, &pemit[wave][row][c8], 16);
        *(uint4*)(pb + (size_t)(q0+row)*NK + n0 + c8) = v;
      }
    }
  }
}

// ---------------- fused setup: zring(XPM) | zring(SAPM+SCPM) | padx | wt2-big ----------------
// (CEN zero must NOT live here: CEN aliases the WTT span — round-12 bug.)
constexpr int SB_Z1 = 8704;            // zring XPM: 4352 rows x 2 slabs
constexpr int SB_Z2 = SB_Z1 + 17408;   // zring SAPM: 4352 rows x 4 slabs
constexpr int SB_PX = SB_Z2 + 3648;    // padx: 57 x 32 x 2
constexpr int SB_WT = SB_PX + 8192;    // wt2 big: 4096 x 2
__global__ __launch_bounds__(256) void k_setup(const float* __restrict__ x, u16* __restrict__ xpm,
    u16* __restrict__ sapm, const float* __restrict__ w_s0, const float* __restrict__ w_c0,
    u16* __restrict__ wtt){
  __shared__ alignas(16) u16 t[64][72];
  const int b = blockIdx.x, tid = threadIdx.x;
  if (b < SB_Z1){
    const int row = b % 4352, slab = b / 4352;
    bool z = (row < GUARD || row >= GUARD+PP) ? true : !interior(row - GUARD);
    if (!z) return;
    u16* p = xpm + (size_t)slab*((long)(PP+2*GUARD)*CIN) + (size_t)row*CIN;
    for (int i = tid*8; i < CIN; i += 2048){ uint4 zz={0,0,0,0}; *(uint4*)(p+i)=zz; }
  } else if (b < SB_Z2){
    const int idx = b - SB_Z1;
    const int row = idx % 4352, slab = idx / 4352;
    bool z = (row < GUARD || row >= GUARD+PP) ? true : !interior(row - GUARD);
    if (!z) return;
    u16* p = sapm + (size_t)slab*((long)(PP+2*GUARD)*CI) + (size_t)row*CI;
    for (int i = tid*8; i < CI; i += 2048){ uint4 zz={0,0,0,0}; *(uint4*)(p+i)=zz; }
  } else if (b < SB_PX){
    const int idx = b - SB_Z2;
    const int n0 = (idx % 57)*64, c0 = ((idx/57) % 32)*64, bb = idx/(57*32);
    const float* xb = x + (size_t)bb*CIN*NPIX;
    u16* ob = xpm + (size_t)bb*(PP+2*GUARD)*CIN + (size_t)GUARD*CIN;
#pragma unroll
    for(int pass=0; pass<2; ++pass){
      const int cl = pass*32 + (tid>>3);
      const int nn = (tid&7)*8;
      const int n = n0 + nn;
      const float* src = xb + (size_t)(c0+cl)*NPIX + n;
      u16 r[8];
      if (n + 7 < NPIX){
        const float4 v0 = *(const float4*)src;
        const float4 v1 = *(const float4*)(src+4);
        r[0]=f2b(v0.x); r[1]=f2b(v0.y); r[2]=f2b(v0.z); r[3]=f2b(v0.w);
        r[4]=f2b(v1.x); r[5]=f2b(v1.y); r[6]=f2b(v1.z); r[7]=f2b(v1.w);
      } else {
#pragma unroll
        for(int j=0;j<8;j++){ const int nj=n+j; r[j] = (nj<NPIX)? f2b(src[j]) : (u16)0; }
      }
      __builtin_memcpy(&t[cl][nn], r, 16);
    }
    __syncthreads();
#pragma unroll
    for(int pass=0; pass<2; ++pass){
      const int nl = pass*32 + (tid>>3);
      const int cc = (tid&7)*8;
      const int n = n0 + nl;
      if (n < NPIX){
        u16 v[8];
#pragma unroll
        for(int j=0;j<8;j++) v[j] = t[cc+j][nl];
        uint4 vv; __builtin_memcpy(&vv, v, 16);
        *(uint4*)(ob + (size_t)pad_of(n)*CIN + c0 + cc) = vv;
      }
    }
  } else {
    const int idx4 = b - SB_PX;
    const float* w = (idx4 >= 4096) ? w_c0 : w_s0;
    u16* wt = wtt + ((idx4 >= 4096) ? (size_t)512*9*2048 : 0);
    const int idx = (idx4 & 4095)*256 + tid;
    const int o = idx >> 11, i = idx & 2047;
    u16 v[9];
#pragma unroll
    for(int s=0;s<9;s++) v[s] = f2b(w[(size_t)idx*9 + s]);
#pragma unroll
    for(int s=0;s<9;s++) wt[(size_t)o*9*2048 + (size_t)s*2048 + i] = v[s];
  }
}

// ---------------- fused late weight prep: wt2(s1)+wt2(c1) | whead ----------------
__global__ __launch_bounds__(256) void k_wprep(const float* __restrict__ w_s1, const float* __restrict__ w_c1,
    u16* __restrict__ wt1, u16* __restrict__ wt2,
    const float* __restrict__ w6, const float* __restrict__ w7, const float* __restrict__ w8,
    u16* __restrict__ wh){
  const int b = blockIdx.x, tid = threadIdx.x;
  if (b < 2048){
    const float* w = (b >= 1024) ? w_c1 : w_s1;
    u16* wt = (b >= 1024) ? wt2 : wt1;
    const int idx = (b & 1023)*256 + tid;
    const int o = idx >> 9, i = idx & 511;
    u16 v[9];
#pragma unroll
    for(int s=0;s<9;s++) v[s] = f2b(w[(size_t)idx*9 + s]);
#pragma unroll
    for(int s=0;s<9;s++) wt[(size_t)o*9*512 + (size_t)s*512 + i] = v[s];
  } else {
    const int idx = (b - 2048)*256 + tid;   // 120*1024
    const int r = idx >> 10, k = idx & 1023;
    float v = 0.f;
    if (r < 40) v = w8[r*512 + (k & 511)];
    else if (r < 80){ if (k < 512) v = w6[(r-40)*512 + k]; }
    else { if (k >= 512) v = w7[(r-80)*512 + (k-512)]; }
    wh[idx] = f2b(v);
  }
}

// ---------------- bf16 [rows, 512] pixel-major -> [512, NK] channel-major (zero tail) ----------------
template<bool PADIN>
__global__ __launch_bounds__(256) void k_to_cm(const u16* __restrict__ in, u16* __restrict__ out,
                                               long sIn, long sOut){
  __shared__ alignas(16) u16 t[64][72];
  const int n0 = blockIdx.x*64, c0 = blockIdx.y*64, b = blockIdx.z;
  const u16* ib = in + (size_t)b*sIn;
  u16* ob = out + (size_t)b*sOut;
  const int tid = threadIdx.x;
#pragma unroll
  for(int pass=0; pass<2; ++pass){
    const int nl = pass*32 + (tid>>3);
    const int cc = (tid&7)*8;
    const int n = n0 + nl;
    uint4 v = {0,0,0,0};
    if (n < NPIX){
      const int r = PADIN ? pad_of(n) : n;
      v = *(const uint4*)(ib + (size_t)r*CI + c0 + cc);
    }
    *(uint4*)&t[nl][cc] = v;
  }
  __syncthreads();
#pragma unroll
  for(int pass=0; pass<2; ++pass){
    const int cl = pass*32 + (tid>>3);
    const int nn = (tid&7)*8;
    const int n = n0 + nn;
    if (n < NK){
      u16 v[8];
#pragma unroll
      for(int j=0;j<8;j++) v[j] = t[nn+j][cl];
      uint4 vv; __builtin_memcpy(&vv, v, 16);
      *(uint4*)(ob + (size_t)(c0+cl)*NK + n) = vv;
    }
  }
}

// ---------------- f32 -> bf16, three concatenated sources ----------------
__global__ __launch_bounds__(256) void k_cvt3(const float* __restrict__ a, int na,
                                              const float* __restrict__ b, int nb,
                                              const float* __restrict__ c, int nc,
                                              u16* __restrict__ dst){
  const int i = blockIdx.x*256 + threadIdx.x;
  float v;
  if (i < na) v = a[i];
  else if (i < na+nb) v = b[i-na];
  else if (i < na+nb+nc) v = c[i-na-nb];
  else return;
  dst[i] = f2b(v);
}

// ---------------- channel softmax ----------------
__global__ __launch_bounds__(256) void k_csoftmax(const float* __restrict__ cen, u16* __restrict__ catt){
  const int c = blockIdx.x, b = blockIdx.y, tid = threadIdx.x;
  const float* e = cen + ((size_t)b*CI + c)*CI;
  u16* o = catt + ((size_t)b*CI + c)*CI;
  __shared__ float red[8];
  const float a0 = e[tid], a1 = e[tid+256];
  float lmin = fminf(a0,a1);
  lmin = wred_min(lmin);
  if((tid&63)==0) red[tid>>6]=lmin;
  __syncthreads();
  const float m0 = fminf(fminf(red[0],red[1]),fminf(red[2],red[3]));
  const float x0 = __expf(m0-a0), x1 = __expf(m0-a1);
  float ls = x0+x1;
  ls = wred_sum(ls);
  if((tid&63)==0) red[4+(tid>>6)]=ls;
  __syncthreads();
  const float inv = 1.f/(red[4]+red[5]+red[6]+red[7]);
  o[tid] = f2b(x0*inv); o[tid+256] = f2b(x1*inv);
}

// ---------------- PV epilogue: SAPM[pad(n),c] = gamma*SAF[n,c] + F1[pad(n),c] ----------------
__global__ __launch_bounds__(256) void k_pv_ep(const float* __restrict__ saf, const u16* __restrict__ f1,
                                               u16* __restrict__ sapm, const float* __restrict__ gamma){
  const int idx = blockIdx.x*256 + threadIdx.x;   // 230400 threads, 8 elems each
  const int n = idx >> 6, c = (idx & 63) * 8;
  const float gam = *gamma;
  const int p = pad_of(n);
  const float4 v0 = *(const float4*)(saf + (size_t)n*CI + c);
  const float4 v1 = *(const float4*)(saf + (size_t)n*CI + c + 4);
  const uint4 rv = *(const uint4*)(f1 + (size_t)p*CI + c);
  const u16* rp = (const u16*)&rv;
  u16 o[8];
  o[0]=f2b(gam*v0.x + b2f(rp[0])); o[1]=f2b(gam*v0.y + b2f(rp[1]));
  o[2]=f2b(gam*v0.z + b2f(rp[2])); o[3]=f2b(gam*v0.w + b2f(rp[3]));
  o[4]=f2b(gam*v1.x + b2f(rp[4])); o[5]=f2b(gam*v1.y + b2f(rp[5]));
  o[6]=f2b(gam*v1.z + b2f(rp[6])); o[7]=f2b(gam*v1.w + b2f(rp[7]));
  uint4 ov; __builtin_memcpy(&ov, o, 16);
  *(uint4*)(sapm + (size_t)p*CI + c) = ov;
}

// ---------------- launch ----------------
extern "C" void kernel_launch(void* const* d_in, const int* in_sizes, int n_in,
                              void* d_out, int out_size, void* d_ws, size_t ws_size,
                              hipStream_t stream){
  (void)in_sizes; (void)n_in; (void)out_size;
  if (ws_size < WS_NEED) return;

  const float* x    = (const float*)d_in[0];
  const float* dd   = (const float*)d_in[1];
  const float* w_s0 = (const float*)d_in[2];
  const float* bn_s0= (const float*)d_in[3];
  const float* wq   = (const float*)d_in[4];
  const float* bq   = (const float*)d_in[5];
  const float* wk   = (const float*)d_in[6];
  const float* bk   = (const float*)d_in[7];
  const float* wv   = (const float*)d_in[8];
  const float* bv   = (const float*)d_in[9];
  const float* gsa  = (const float*)d_in[10];
  const float* lam  = (const float*)d_in[11];
  const float* w_s1 = (const float*)d_in[12];
  const float* bn_s1= (const float*)d_in[13];
  const float* w6   = (const float*)d_in[14];
  const float* b6   = (const float*)d_in[15];
  const float* w_c0 = (const float*)d_in[16];
  const float* bn_c0= (const float*)d_in[17];
  const float* gsc  = (const float*)d_in[18];
  const float* w_c1 = (const float*)d_in[19];
  const float* bn_c1= (const float*)d_in[20];
  const float* w7   = (const float*)d_in[21];
  const float* b7   = (const float*)d_in[22];
  const float* w8   = (const float*)d_in[23];
  const float* b8   = (const float*)d_in[24];

  char* W = (char*)d_ws;
  u16*   XPM   = (u16*)(W + OFF_XPM);
  float* SAF   = (float*)(W + OFF_SAF);
  u16*   PB    = (u16*)(W + OFF_PBUF);
  u16*   SACONV= (u16*)(W + OFF_SACONV);
  u16*   SCCONV= (u16*)(W + OFF_SCCONV);
  u16*   F1    = (u16*)(W + OFF_FEAT1);
  u16*   F2    = (u16*)(W + OFF_FEAT2);
  u16*   SAPM  = (u16*)(W + OFF_SAPM);
  u16*   SCPM  = (u16*)(W + OFF_SCPM);
  u16*   WTT   = (u16*)(W + OFF_W);
  u16*   WQB   = (u16*)(W + OFF_WQB);
  u16*   QC    = (u16*)(W + OFF_QC);
  u16*   KC    = (u16*)(W + OFF_KC);
  u16*   VC    = (u16*)(W + OFF_VC);
  u16*   WT1   = (u16*)(W + OFF_WT1);
  u16*   WT2   = (u16*)(W + OFF_WT2);
  u16*   WH    = (u16*)(W + OFF_WH);
  u16*   VCM   = (u16*)(W + OFF_VCM);
  u16*   F2CM  = VCM;                     // time-shared
  float* CEN   = (float*)(W + OFF_CEN);
  u16*   CATT  = (u16*)(W + OFF_CATT);
  float* OUT   = (float*)d_out;

  // fused setup: ring zeroing + padx + big weight transform (one launch; NO CEN here)
  k_setup<<<dim3(SB_WT),256,0,stream>>>(x, XPM, SAPM, w_s0, w_c0, WTT);

  // conv s0 + c0 fused (N-concat), U=4 (BK=128); grid.x=32 (multiple of 8 — XCD A-sharing)
  GArgs a{};
  a.A = XPM + (size_t)GUARD*CIN; a.B = WTT; a.Cb = F1; a.Cb2 = F2;
  a.bn = bn_s0; a.bn2 = bn_c0;
  a.sA = (long)(PP+2*GUARD)*CIN; a.sB = 0; a.sC = (long)PP*CI;
  a.M = PP; a.N = 1024; a.nsplit = 512; a.KT = 576; a.ktps = 64;
  a.lda = CIN; a.ldb = 9*2048; a.ldc = CI; a.Mclamp = PP-1; a.Nclamp = 1023;
  k_gemm<0,true,true,false,4,false><<<dim3(32,8,2),256,0,stream>>>(a);

  // bf16 copies of 1x1 weights (concat [wq;wk;wv] = 640x512), one launch
  k_cvt3<<<dim3((64*512+64*512+512*512)/256),256,0,stream>>>(wq, 64*512, wk, 64*512, wv, 512*512, WQB);

  // q,k,v in one GEMM (N=640), U=4
  GArgs q{};
  q.A = F1; q.sA = (long)PP*CI; q.lda = CI;
  q.M = PP; q.Mclamp = PP-1; q.KT = 16; q.ktps = 16;
  q.B = WQB; q.sB = 0; q.ldb = CI; q.N = 640; q.Nclamp = 639;
  q.Cb = QC; q.Cb2 = KC; q.Cb3 = VC; q.bias = bq; q.bias2 = bk; q.bias3 = bv;
  k_gemm<6,false,false,false,4,false><<<dim3(32,5,2),256,0,stream>>>(q);

  k_to_cm<false><<<dim3(NK/64, CI/64, 2),256,0,stream>>>(VC, VCM, (long)NPIX*CI, (long)CI*NK);

  // position attention, per batch: fused energy+softmax -> PV(split-K 4) -> epilogue
  for(int bb=0; bb<2; ++bb){
    k_esm<<<dim3(225),512,0,stream>>>(QC + (size_t)bb*NPIX*CQ, KC + (size_t)bb*NPIX*CQ,
                                      dd + (size_t)bb*NPIX, lam, PB);
    hipMemsetAsync(SAF, 0, (size_t)NPIX*CI*4, stream);
    GArgs p{};
    p.A = PB; p.B = VCM + (size_t)bb*CI*NK;
    p.Cf = SAF;
    p.M = NPIX; p.N = CI; p.KT = NK/32; p.ktps = NK/32;
    p.lda = NK; p.ldb = NK; p.ldc = CI; p.sC = 0;
    p.Mclamp = NPIX-1; p.Nclamp = CI-1;
    p.ksplit = 4; p.kps = NK/128;
    k_gemm<3,false,false,false,4,true><<<dim3(29, 4, 4),256,0,stream>>>(p);
    k_pv_ep<<<dim3(NPIX*CI/8/256),256,0,stream>>>(SAF, F1 + (size_t)bb*PP*CI,
                                                  SAPM + (size_t)bb*(PP+2*GUARD)*CI + (size_t)GUARD*CI, gsa);
  }

  // channel attention: Gram with split-K atomics (U=4); CEN zeroed HERE (WTT dead now)
  k_to_cm<true><<<dim3(NK/64, CI/64, 2),256,0,stream>>>(F2, F2CM, (long)PP*CI, (long)CI*NK);
  hipMemsetAsync(CEN, 0, (size_t)2*CI*CI*4, stream);
  GArgs c{};
  c.A = F2CM; c.B = F2CM; c.Cf = CEN;
  c.sA = (long)CI*NK; c.sB = (long)CI*NK; c.sC = (long)CI*CI;
  c.M = CI; c.N = CI; c.KT = NK/32; c.ktps = NK/32;
  c.lda = NK; c.ldb = NK; c.ldc = CI; c.Mclamp = CI-1; c.Nclamp = CI-1;
  c.ksplit = 8; c.kps = (NK/32 + 7)/8;
  k_gemm<3,false,false,false,4,true><<<dim3(4, 4, 16),256,0,stream>>>(c);
  k_csoftmax<<<dim3(CI,2),256,0,stream>>>(CEN, CATT);
  GArgs s{};
  s.A = F2; s.B = CATT;
  s.Cb = SCPM + (size_t)GUARD*CI;
  s.resid = F2; s.gamma = gsc;
  s.sA = (long)PP*CI; s.sB = (long)CI*CI; s.sC = (long)(PP+2*GUARD)*CI; s.sres = (long)PP*CI;
  s.M = PP; s.N = CI; s.KT = 16; s.ktps = 16;
  s.lda = CI; s.ldb = CI; s.ldc = CI; s.Mclamp = PP-1; s.Nclamp = CI-1;
  k_gemm<5,false,false,false,4,false><<<dim3(32, 4, 2),256,0,stream>>>(s);

  // late weight prep (WT1/WT2/WH live in dead-WTT space), then post convs s1 + c1 (DUALZ)
  k_wprep<<<dim3(2048 + 480),256,0,stream>>>(w_s1, w_c1, WT1, WT2, w6, w7, w8, WH);
  GArgs t{};
  t.A = SAPM + (size_t)GUARD*CI; t.A2 = SCPM + (size_t)GUARD*CI;
  t.B = WT1; t.B2 = WT2;
  t.Cb = SACONV; t.Cb2 = SCCONV; t.bn = bn_s1; t.bn2 = bn_c1;
  t.sA = (long)(PP+2*GUARD)*CI; t.sB = 0; t.sC = (long)PP*CI;
  t.M = PP; t.N = CI; t.KT = 144; t.ktps = 16;
  t.lda = CI; t.ldb = 9*512; t.ldc = CI; t.Mclamp = PP-1; t.Nclamp = CI-1;
  k_gemm<0,true,false,true,4,false><<<dim3(32,4,4),256,0,stream>>>(t);

  // fused head GEMM: A=[SACONV|SCCONV] (K=1024), B=WH (N=120), f32 out + bias
  GArgs h{};
  h.A = SACONV; h.A2 = SCCONV; h.B = WH; h.Cf = OUT;
  h.bias = b8; h.bias2 = b6; h.bias3 = b7;
  h.sA = (long)PP*CI; h.sB = 0; h.sC = 0;
  h.M = PP; h.N = 120; h.KT = 32; h.ktps = 32;
  h.lda = CI; h.ldb = 1024; h.ldc = 0; h.Mclamp = PP-1; h.Nclamp = 119;
  k_gemm<7,false,false,false,4,false,true><<<dim3(32,1,2),256,0,stream>>>(h);
}